// Round 1
// baseline (815.054 us; speedup 1.0000x reference)
//
#include <hip/hip_runtime.h>
#include <hip/hip_bf16.h>

// ---------------- helpers ----------------

__device__ __forceinline__ float lrelu02(float x) { return x > 0.f ? x : 0.2f * x; }

// monotonic float<->uint mapping so unsigned atomicMax == float max
__device__ __forceinline__ unsigned fkey(float f) {
    unsigned b = __float_as_uint(f);
    return b ^ ((b & 0x80000000u) ? 0xFFFFFFFFu : 0x80000000u);
}
__device__ __forceinline__ float funkey(unsigned u) {
    unsigned b = u ^ ((u & 0x80000000u) ? 0x80000000u : 0xFFFFFFFFu);
    return __uint_as_float(b);
}

// ---------------- layer 1 GEMM + logits ----------------
__global__ __launch_bounds__(256) void k_gemm1(
    const float* __restrict__ x, const float* __restrict__ W1,
    const float* __restrict__ a_src, const float* __restrict__ a_dst,
    float* __restrict__ H1, float* __restrict__ asrcv, float* __restrict__ adstv, int N)
{
    int col = threadIdx.x & 127;
    int rs  = threadIdx.x >> 7;           // 2 rows per block
    int row = blockIdx.x * 2 + rs;
    if (row >= N) return;
    const float* xr = x + (size_t)row * 128;
    float acc = 0.f;
#pragma unroll 8
    for (int k = 0; k < 128; ++k)
        acc = fmaf(xr[k], W1[k * 128 + col], acc);
    H1[(size_t)row * 128 + col] = acc;
    int head = col >> 5;
    float vs = acc * a_src[col];
    float vd = acc * a_dst[col];
#pragma unroll
    for (int m = 16; m >= 1; m >>= 1) { vs += __shfl_xor(vs, m); vd += __shfl_xor(vd, m); }
    if ((col & 31) == 0) { asrcv[row * 4 + head] = vs; adstv[row * 4 + head] = vd; }
}

// ---------------- layer 2 GEMM + logits (input = relu(out1 + b1)) ----------------
__global__ __launch_bounds__(256) void k_gemm2(
    const float* __restrict__ X, const float* __restrict__ b1,
    const float* __restrict__ W2, const float* __restrict__ a_src2, const float* __restrict__ a_dst2,
    float* __restrict__ H2, float* __restrict__ asrcv, float* __restrict__ adstv, int N)
{
    int c  = threadIdx.x & 15;
    int rs = threadIdx.x >> 4;            // 16 rows per block
    int row = blockIdx.x * 16 + rs;
    if (row >= N) return;
    const float* xr = X + (size_t)row * 128;
    float acc = 0.f;
#pragma unroll 8
    for (int k = 0; k < 128; ++k) {
        float xv = fmaxf(xr[k] + b1[k], 0.f);
        acc = fmaf(xv, W2[k * 16 + c], acc);
    }
    H2[(size_t)row * 16 + c] = acc;
    float vs = acc * a_src2[c];
    float vd = acc * a_dst2[c];
#pragma unroll
    for (int m = 8; m >= 1; m >>= 1) { vs += __shfl_xor(vs, m); vd += __shfl_xor(vd, m); }
    if (c == 0) { asrcv[row] = vs; adstv[row] = vd; }
}

// ---------------- softmax node/edge passes ----------------

__global__ __launch_bounds__(256) void k_nodeA(
    const float* __restrict__ asrcv, const float* __restrict__ adstv,
    float* __restrict__ vself, unsigned* __restrict__ mkey, int NH)
{
    int i = blockIdx.x * 256 + threadIdx.x;
    if (i >= NH) return;
    float v = lrelu02(asrcv[i] + adstv[i]);
    vself[i] = v;
    mkey[i] = fkey(v);
}

template <int H>
__global__ __launch_bounds__(256) void k_edgeA(
    const int* __restrict__ src, const int* __restrict__ dst,
    const float* __restrict__ asrcv, const float* __restrict__ adstv,
    unsigned* __restrict__ mkey, int E)
{
    int i = blockIdx.x * 256 + threadIdx.x;
    if (i >= E * H) return;
    int e = (H == 1) ? i : (i >> 2);
    int h = (H == 1) ? 0 : (i & 3);
    int s = src[e], d = dst[e];
    float v = lrelu02(asrcv[s * H + h] + adstv[d * H + h]);
    atomicMax(&mkey[d * H + h], fkey(v));
}

__global__ __launch_bounds__(256) void k_nodeB(
    const float* __restrict__ vself, unsigned* __restrict__ mkey,
    float* __restrict__ pself, float* __restrict__ ssum, int NH)
{
    int i = blockIdx.x * 256 + threadIdx.x;
    if (i >= NH) return;
    float m = funkey(mkey[i]);
    ((float*)mkey)[i] = m;
    float p = expf(vself[i] - m);
    pself[i] = p;
    ssum[i]  = p;
}

template <int H>
__global__ __launch_bounds__(256) void k_edgeB(
    const int* __restrict__ src, const int* __restrict__ dst,
    const float* __restrict__ asrcv, const float* __restrict__ adstv,
    const float* __restrict__ m, float* __restrict__ ssum, int E)
{
    int i = blockIdx.x * 256 + threadIdx.x;
    if (i >= E * H) return;
    int e = (H == 1) ? i : (i >> 2);
    int h = (H == 1) ? 0 : (i & 3);
    int s = src[e], d = dst[e];
    float v = lrelu02(asrcv[s * H + h] + adstv[d * H + h]);
    atomicAdd(&ssum[d * H + h], expf(v - m[d * H + h]));
}

template <int H, int C>
__global__ __launch_bounds__(256) void k_nodeC(
    const float* __restrict__ Hmat, const float* __restrict__ pself,
    const float* __restrict__ ssum, float* __restrict__ out, int N)
{
    const int HC = H * C;
    int i = blockIdx.x * 256 + threadIdx.x;
    if (i >= N * HC) return;
    int n = i / HC;
    int h = (i % HC) / C;
    float a = pself[n * H + h] / (ssum[n * H + h] + 1e-16f);
    out[i] = a * Hmat[i];
}

template <int H, int C>
__global__ __launch_bounds__(256) void k_edgeC(
    const int* __restrict__ src, const int* __restrict__ dst,
    const float* __restrict__ asrcv, const float* __restrict__ adstv,
    const float* __restrict__ m, const float* __restrict__ ssum,
    const float* __restrict__ Hmat, float* __restrict__ out, int E)
{
    const int HC = H * C;
    int i = blockIdx.x * 256 + threadIdx.x;
    if (i >= E * HC) return;
    int e  = i / HC;
    int hc = i % HC;
    int h  = hc / C;
    int s = src[e], d = dst[e];
    float v = lrelu02(asrcv[s * H + h] + adstv[d * H + h]);
    float alpha = expf(v - m[d * H + h]) / (ssum[d * H + h] + 1e-16f);
    atomicAdd(&out[(size_t)d * HC + hc], alpha * Hmat[(size_t)s * HC + hc]);
}

// ---------------- pooling (sorted nodeIDs -> per-graph binary search) ----------------
__global__ __launch_bounds__(256) void k_pool(
    const float* __restrict__ out2, const float* __restrict__ b2,
    const int* __restrict__ nodeIDs, float* __restrict__ pooled, int N)
{
    int g = blockIdx.x;
    int lo = 0, hi = N;
    while (lo < hi) { int mid = (lo + hi) >> 1; if (nodeIDs[mid] < g) lo = mid + 1; else hi = mid; }
    int start = lo;
    lo = 0; hi = N;
    while (lo < hi) { int mid = (lo + hi) >> 1; if (nodeIDs[mid] < g + 1) lo = mid + 1; else hi = mid; }
    int end = lo;

    int c = threadIdx.x & 15, grp = threadIdx.x >> 4;
    float bc = b2[c];
    float acc = 0.f;
    for (int n = start + grp; n < end; n += 16)
        acc += fmaxf(out2[(size_t)n * 16 + c] + bc, 0.f);

    __shared__ float sd[256];
    sd[threadIdx.x] = acc;
    __syncthreads();
#pragma unroll
    for (int s = 8; s >= 1; s >>= 1) {
        if (grp < s) sd[threadIdx.x] += sd[(grp + s) * 16 + c];
        __syncthreads();
    }
    if (threadIdx.x < 16) {
        float cnt = (float)(end - start);
        pooled[g * 16 + threadIdx.x] = sd[threadIdx.x] / fmaxf(cnt, 1.f);
    }
}

// ---------------- final linear ----------------
__global__ __launch_bounds__(256) void k_final(
    const float* __restrict__ pooled, const float* __restrict__ Wf,
    const float* __restrict__ bf, float* __restrict__ outp, int G)
{
    int i = blockIdx.x * 256 + threadIdx.x;
    if (i >= G * 64) return;
    int g = i >> 6, o = i & 63;
    float acc = bf[o];
#pragma unroll
    for (int k = 0; k < 16; ++k)
        acc = fmaf(pooled[g * 16 + k], Wf[k * 64 + o], acc);
    outp[i] = acc;
}

// ---------------- launcher ----------------
extern "C" void kernel_launch(void* const* d_in, const int* in_sizes, int n_in,
                              void* d_out, int out_size, void* d_ws, size_t ws_size,
                              hipStream_t stream)
{
    const float* x   = (const float*)d_in[0];
    const int*   ei  = (const int*)  d_in[1];
    const int*   nid = (const int*)  d_in[3];
    const float* W1  = (const float*)d_in[4];
    const float* as1 = (const float*)d_in[5];
    const float* ad1 = (const float*)d_in[6];
    const float* b1  = (const float*)d_in[7];
    const float* W2  = (const float*)d_in[8];
    const float* as2 = (const float*)d_in[9];
    const float* ad2 = (const float*)d_in[10];
    const float* b2  = (const float*)d_in[11];
    const float* Wf  = (const float*)d_in[12];
    const float* bf  = (const float*)d_in[13];
    float* outp = (float*)d_out;

    const int N = in_sizes[0] / 128;
    const int E = in_sizes[1] / 2;
    const int G = out_size / 64;
    const int* src = ei;
    const int* dst = ei + E;

    char* ws = (char*)d_ws;
    size_t off = 0;
    auto alloc = [&](size_t bytes) -> char* {
        char* p = ws + off;
        off += (bytes + 255) & ~(size_t)255;
        return p;
    };

    float*    H1     = (float*)   alloc((size_t)N * 128 * 4);
    float*    asrc1  = (float*)   alloc((size_t)N * 4 * 4);
    float*    adst1  = (float*)   alloc((size_t)N * 4 * 4);
    float*    vself1 = (float*)   alloc((size_t)N * 4 * 4);
    unsigned* mkey1  = (unsigned*)alloc((size_t)N * 4 * 4);
    float*    pself1 = (float*)   alloc((size_t)N * 4 * 4);
    float*    ssum1  = (float*)   alloc((size_t)N * 4 * 4);
    float*    out1   = (float*)   alloc((size_t)N * 128 * 4);
    float*    H2     = (float*)   alloc((size_t)N * 16 * 4);
    float*    asrc2  = (float*)   alloc((size_t)N * 4);
    float*    adst2  = (float*)   alloc((size_t)N * 4);
    float*    vself2 = (float*)   alloc((size_t)N * 4);
    unsigned* mkey2  = (unsigned*)alloc((size_t)N * 4);
    float*    pself2 = (float*)   alloc((size_t)N * 4);
    float*    ssum2  = (float*)   alloc((size_t)N * 4);
    float*    out2   = (float*)   alloc((size_t)N * 16 * 4);
    float*    pooled = (float*)   alloc((size_t)G * 16 * 4);

    auto cdiv = [](long long a, long long b) { return (int)((a + b - 1) / b); };

    // ----- layer 1 -----
    k_gemm1<<<cdiv(N, 2), 256, 0, stream>>>(x, W1, as1, ad1, H1, asrc1, adst1, N);
    k_nodeA<<<cdiv((long long)N * 4, 256), 256, 0, stream>>>(asrc1, adst1, vself1, mkey1, N * 4);
    k_edgeA<4><<<cdiv((long long)E * 4, 256), 256, 0, stream>>>(src, dst, asrc1, adst1, mkey1, E);
    k_nodeB<<<cdiv((long long)N * 4, 256), 256, 0, stream>>>(vself1, mkey1, pself1, ssum1, N * 4);
    k_edgeB<4><<<cdiv((long long)E * 4, 256), 256, 0, stream>>>(src, dst, asrc1, adst1, (const float*)mkey1, ssum1, E);
    k_nodeC<4, 32><<<cdiv((long long)N * 128, 256), 256, 0, stream>>>(H1, pself1, ssum1, out1, N);
    k_edgeC<4, 32><<<cdiv((long long)E * 128, 256), 256, 0, stream>>>(src, dst, asrc1, adst1, (const float*)mkey1, ssum1, H1, out1, E);

    // ----- layer 2 -----
    k_gemm2<<<cdiv(N, 16), 256, 0, stream>>>(out1, b1, W2, as2, ad2, H2, asrc2, adst2, N);
    k_nodeA<<<cdiv(N, 256), 256, 0, stream>>>(asrc2, adst2, vself2, mkey2, N);
    k_edgeA<1><<<cdiv(E, 256), 256, 0, stream>>>(src, dst, asrc2, adst2, mkey2, E);
    k_nodeB<<<cdiv(N, 256), 256, 0, stream>>>(vself2, mkey2, pself2, ssum2, N);
    k_edgeB<1><<<cdiv(E, 256), 256, 0, stream>>>(src, dst, asrc2, adst2, (const float*)mkey2, ssum2, E);
    k_nodeC<1, 16><<<cdiv((long long)N * 16, 256), 256, 0, stream>>>(H2, pself2, ssum2, out2, N);
    k_edgeC<1, 16><<<cdiv((long long)E * 16, 256), 256, 0, stream>>>(src, dst, asrc2, adst2, (const float*)mkey2, ssum2, H2, out2, E);

    // ----- pool + final linear -----
    k_pool<<<G, 256, 0, stream>>>(out2, b2, nid, pooled, N);
    k_final<<<cdiv((long long)G * 64, 256), 256, 0, stream>>>(pooled, Wf, bf, outp, G);
}

// Round 2
// 500.772 us; speedup vs baseline: 1.6276x; 1.6276x over previous
//
#include <hip/hip_runtime.h>
#include <hip/hip_bf16.h>

// ---------------- helpers ----------------

__device__ __forceinline__ float lrelu02(float x) { return x > 0.f ? x : 0.2f * x; }

// ---------------- layer 1 GEMM + logits ----------------
// H1[n,128] = x[n,:] @ W1 ; asrc[n,h] = sum_c H1[n,h,c]*a_src[h,c] (likewise adst)
__global__ __launch_bounds__(256) void k_gemm1(
    const float* __restrict__ x, const float* __restrict__ W1,
    const float* __restrict__ a_src, const float* __restrict__ a_dst,
    float* __restrict__ H1, float* __restrict__ asrcv, float* __restrict__ adstv, int N)
{
    int col = threadIdx.x & 127;
    int rs  = threadIdx.x >> 7;           // 2 rows per block
    int row = blockIdx.x * 2 + rs;
    if (row >= N) return;
    const float* xr = x + (size_t)row * 128;
    float acc = 0.f;
#pragma unroll 8
    for (int k = 0; k < 128; ++k)
        acc = fmaf(xr[k], W1[k * 128 + col], acc);
    H1[(size_t)row * 128 + col] = acc;
    int head = col >> 5;
    float vs = acc * a_src[col];
    float vd = acc * a_dst[col];
#pragma unroll
    for (int m = 16; m >= 1; m >>= 1) { vs += __shfl_xor(vs, m); vd += __shfl_xor(vd, m); }
    if ((col & 31) == 0) { asrcv[row * 4 + head] = vs; adstv[row * 4 + head] = vd; }
}

// ---------------- layer 2 GEMM + logits (input = relu(out1 + b1)) ----------------
__global__ __launch_bounds__(256) void k_gemm2(
    const float* __restrict__ X, const float* __restrict__ b1,
    const float* __restrict__ W2, const float* __restrict__ a_src2, const float* __restrict__ a_dst2,
    float* __restrict__ H2, float* __restrict__ asrcv, float* __restrict__ adstv, int N)
{
    int c  = threadIdx.x & 15;
    int rs = threadIdx.x >> 4;            // 16 rows per block
    int row = blockIdx.x * 16 + rs;
    if (row >= N) return;
    const float* xr = X + (size_t)row * 128;
    float acc = 0.f;
#pragma unroll 8
    for (int k = 0; k < 128; ++k) {
        float xv = fmaxf(xr[k] + b1[k], 0.f);
        acc = fmaf(xv, W2[k * 16 + c], acc);
    }
    H2[(size_t)row * 16 + c] = acc;
    float vs = acc * a_src2[c];
    float vd = acc * a_dst2[c];
#pragma unroll
    for (int m = 8; m >= 1; m >>= 1) { vs += __shfl_xor(vs, m); vd += __shfl_xor(vd, m); }
    if (c == 0) { asrcv[row] = vs; adstv[row] = vd; }
}

// ---------------- CSR build ----------------
__global__ __launch_bounds__(256) void k_hist(
    const int* __restrict__ dst, int* __restrict__ deg, int E)
{
    int i = blockIdx.x * 256 + threadIdx.x;
    if (i < E) atomicAdd(&deg[dst[i]], 1);
}

// single-block two-level (shfl + LDS) exclusive scan: off[0]=0, off[i+1]=sum(deg[0..i])
__global__ __launch_bounds__(1024) void k_scan(
    const int* __restrict__ deg, int* __restrict__ off, int N)
{
    __shared__ int wsum[16];
    __shared__ int carry_s;
    const int lane = threadIdx.x & 63, w = threadIdx.x >> 6;
    if (threadIdx.x == 0) carry_s = 0;
    __syncthreads();
    for (int base = 0; base < N; base += 1024) {
        int i = base + threadIdx.x;
        int v = (i < N) ? deg[i] : 0;
        int sc = v;
#pragma unroll
        for (int s = 1; s < 64; s <<= 1) {
            int t = __shfl_up(sc, s);
            if (lane >= s) sc += t;
        }
        if (lane == 63) wsum[w] = sc;
        __syncthreads();
        if (threadIdx.x < 16) {
            int t = wsum[threadIdx.x];
#pragma unroll
            for (int s = 1; s < 16; s <<= 1) {
                int u = __shfl_up(t, s);
                if ((int)threadIdx.x >= s) t += u;
            }
            wsum[threadIdx.x] = t;
        }
        __syncthreads();
        int carry = carry_s;
        int woff  = (w == 0) ? 0 : wsum[w - 1];
        if (i < N) off[i + 1] = carry + woff + sc;
        __syncthreads();
        if (threadIdx.x == 0) carry_s = carry + wsum[15];
        __syncthreads();
    }
    if (threadIdx.x == 0) off[0] = 0;
}

__global__ __launch_bounds__(256) void k_scatter(
    const int* __restrict__ src, const int* __restrict__ dst,
    const int* __restrict__ off, int* __restrict__ cur,
    int* __restrict__ ecsr, int E)
{
    int i = blockIdx.x * 256 + threadIdx.x;
    if (i >= E) return;
    int d = dst[i];
    int p = off[d] + atomicAdd(&cur[d], 1);
    ecsr[p] = src[i];
}

// ---------------- fused per-node softmax + aggregation ----------------
// layer 1: H=4 heads, C=32 ch. One wave per node. No atomics.
__global__ __launch_bounds__(256) void k_agg1(
    const float* __restrict__ H1, const float* __restrict__ asrc, const float* __restrict__ adst,
    const int* __restrict__ off, const int* __restrict__ ecsr,
    float* __restrict__ out, int N)
{
    const int w = threadIdx.x >> 6, lane = threadIdx.x & 63;
    const int n = blockIdx.x * 4 + w;
    if (n >= N) return;
    const int beg = off[n], deg = off[n + 1] - beg;

    const float4 ad4 = *(const float4*)&adst[n * 4];
    const float4 as4 = *(const float4*)&asrc[n * 4];
    const float ad[4] = { ad4.x, ad4.y, ad4.z, ad4.w };
    float vself[4] = { lrelu02(as4.x + ad4.x), lrelu02(as4.y + ad4.y),
                       lrelu02(as4.z + ad4.z), lrelu02(as4.w + ad4.w) };
    // phase A: segment max (self included)
    float m[4] = { vself[0], vself[1], vself[2], vself[3] };
    for (int j = lane; j < deg; j += 64) {
        int s = ecsr[beg + j];
        const float4 a = *(const float4*)&asrc[s * 4];
        m[0] = fmaxf(m[0], lrelu02(a.x + ad[0]));
        m[1] = fmaxf(m[1], lrelu02(a.y + ad[1]));
        m[2] = fmaxf(m[2], lrelu02(a.z + ad[2]));
        m[3] = fmaxf(m[3], lrelu02(a.w + ad[3]));
    }
#pragma unroll
    for (int xm = 32; xm >= 1; xm >>= 1) {
        m[0] = fmaxf(m[0], __shfl_xor(m[0], xm));
        m[1] = fmaxf(m[1], __shfl_xor(m[1], xm));
        m[2] = fmaxf(m[2], __shfl_xor(m[2], xm));
        m[3] = fmaxf(m[3], __shfl_xor(m[3], xm));
    }
    // phase B: segment exp-sum
    float ss[4] = { 0.f, 0.f, 0.f, 0.f };
    for (int j = lane; j < deg; j += 64) {
        int s = ecsr[beg + j];
        const float4 a = *(const float4*)&asrc[s * 4];
        ss[0] += __expf(lrelu02(a.x + ad[0]) - m[0]);
        ss[1] += __expf(lrelu02(a.y + ad[1]) - m[1]);
        ss[2] += __expf(lrelu02(a.z + ad[2]) - m[2]);
        ss[3] += __expf(lrelu02(a.w + ad[3]) - m[3]);
    }
#pragma unroll
    for (int xm = 32; xm >= 1; xm >>= 1) {
        ss[0] += __shfl_xor(ss[0], xm);
        ss[1] += __shfl_xor(ss[1], xm);
        ss[2] += __shfl_xor(ss[2], xm);
        ss[3] += __shfl_xor(ss[3], xm);
    }
    float inv[4], aself[4];
#pragma unroll
    for (int h = 0; h < 4; ++h) {
        float e = __expf(vself[h] - m[h]);
        inv[h]   = 1.f / (ss[h] + e + 1e-16f);
        aself[h] = e * inv[h];
    }
    // phase C: out[n,c] = aself*H1[n,c] + sum_e alpha_e*H1[src_e,c]; 2 ch/lane
    const int c2 = lane * 2;
    const int h  = lane >> 4;            // (2*lane)/32
    const float mh = m[h], ih = inv[h], adh = ad[h];
    const float2 hself = *(const float2*)&H1[(size_t)n * 128 + c2];
    float accx = aself[h] * hself.x, accy = aself[h] * hself.y;
    int s = (deg > 0) ? ecsr[beg] : 0;
    for (int j = 0; j < deg; ++j) {
        int snext = (j + 1 < deg) ? ecsr[beg + j + 1] : 0;
        float a  = asrc[s * 4 + h];
        float2 v = *(const float2*)&H1[(size_t)s * 128 + c2];
        float al = __expf(lrelu02(a + adh) - mh) * ih;
        accx += al * v.x;
        accy += al * v.y;
        s = snext;
    }
    *(float2*)&out[(size_t)n * 128 + c2] = make_float2(accx, accy);
}

// layer 2: H=1, C=16. One wave per node; 4 edge-groups x 16 channels.
__global__ __launch_bounds__(256) void k_agg2(
    const float* __restrict__ H2, const float* __restrict__ asrc, const float* __restrict__ adst,
    const int* __restrict__ off, const int* __restrict__ ecsr,
    float* __restrict__ out, int N)
{
    const int w = threadIdx.x >> 6, lane = threadIdx.x & 63;
    const int n = blockIdx.x * 4 + w;
    if (n >= N) return;
    const int beg = off[n], deg = off[n + 1] - beg;

    const float adv = adst[n];
    const float vself = lrelu02(asrc[n] + adv);
    float m = vself;
    for (int j = lane; j < deg; j += 64)
        m = fmaxf(m, lrelu02(asrc[ecsr[beg + j]] + adv));
#pragma unroll
    for (int xm = 32; xm >= 1; xm >>= 1) m = fmaxf(m, __shfl_xor(m, xm));
    float ssum = 0.f;
    for (int j = lane; j < deg; j += 64)
        ssum += __expf(lrelu02(asrc[ecsr[beg + j]] + adv) - m);
#pragma unroll
    for (int xm = 32; xm >= 1; xm >>= 1) ssum += __shfl_xor(ssum, xm);
    float eself = __expf(vself - m);
    float inv = 1.f / (ssum + eself + 1e-16f);

    const int c = lane & 15, g = lane >> 4;
    float acc = (g == 0) ? (eself * inv) * H2[(size_t)n * 16 + c] : 0.f;
    for (int j = g; j < deg; j += 4) {
        int s = ecsr[beg + j];
        float al = __expf(lrelu02(asrc[s] + adv) - m) * inv;
        acc += al * H2[(size_t)s * 16 + c];
    }
    acc += __shfl_xor(acc, 16);
    acc += __shfl_xor(acc, 32);
    if (g == 0) out[(size_t)n * 16 + c] = acc;
}

// ---------------- pooling (sorted nodeIDs -> per-graph binary search) ----------------
__global__ __launch_bounds__(256) void k_pool(
    const float* __restrict__ out2, const float* __restrict__ b2,
    const int* __restrict__ nodeIDs, float* __restrict__ pooled, int N)
{
    int g = blockIdx.x;
    int lo = 0, hi = N;
    while (lo < hi) { int mid = (lo + hi) >> 1; if (nodeIDs[mid] < g) lo = mid + 1; else hi = mid; }
    int start = lo;
    lo = 0; hi = N;
    while (lo < hi) { int mid = (lo + hi) >> 1; if (nodeIDs[mid] < g + 1) lo = mid + 1; else hi = mid; }
    int end = lo;

    int c = threadIdx.x & 15, grp = threadIdx.x >> 4;
    float bc = b2[c];
    float acc = 0.f;
    for (int n = start + grp; n < end; n += 16)
        acc += fmaxf(out2[(size_t)n * 16 + c] + bc, 0.f);

    __shared__ float sd[256];
    sd[threadIdx.x] = acc;
    __syncthreads();
#pragma unroll
    for (int s = 8; s >= 1; s >>= 1) {
        if (grp < s) sd[threadIdx.x] += sd[(grp + s) * 16 + c];
        __syncthreads();
    }
    if (threadIdx.x < 16) {
        float cnt = (float)(end - start);
        pooled[g * 16 + threadIdx.x] = sd[threadIdx.x] / fmaxf(cnt, 1.f);
    }
}

// ---------------- final linear ----------------
__global__ __launch_bounds__(256) void k_final(
    const float* __restrict__ pooled, const float* __restrict__ Wf,
    const float* __restrict__ bf, float* __restrict__ outp, int G)
{
    int i = blockIdx.x * 256 + threadIdx.x;
    if (i >= G * 64) return;
    int g = i >> 6, o = i & 63;
    float acc = bf[o];
#pragma unroll
    for (int k = 0; k < 16; ++k)
        acc = fmaf(pooled[g * 16 + k], Wf[k * 64 + o], acc);
    outp[i] = acc;
}

// ---------------- launcher ----------------
extern "C" void kernel_launch(void* const* d_in, const int* in_sizes, int n_in,
                              void* d_out, int out_size, void* d_ws, size_t ws_size,
                              hipStream_t stream)
{
    const float* x   = (const float*)d_in[0];
    const int*   ei  = (const int*)  d_in[1];
    const int*   nid = (const int*)  d_in[3];
    const float* W1  = (const float*)d_in[4];
    const float* as1 = (const float*)d_in[5];
    const float* ad1 = (const float*)d_in[6];
    const float* b1  = (const float*)d_in[7];
    const float* W2  = (const float*)d_in[8];
    const float* as2 = (const float*)d_in[9];
    const float* ad2 = (const float*)d_in[10];
    const float* b2  = (const float*)d_in[11];
    const float* Wf  = (const float*)d_in[12];
    const float* bf  = (const float*)d_in[13];
    float* outp = (float*)d_out;

    const int N = in_sizes[0] / 128;
    const int E = in_sizes[1] / 2;
    const int G = out_size / 64;
    const int* src = ei;
    const int* dst = ei + E;

    char* ws = (char*)d_ws;
    size_t off_b = 0;
    auto alloc = [&](size_t bytes) -> char* {
        char* p = ws + off_b;
        off_b += (bytes + 255) & ~(size_t)255;
        return p;
    };

    float* H1     = (float*)alloc((size_t)N * 128 * 4);
    float* out1   = (float*)alloc((size_t)N * 128 * 4);
    float* asrc1  = (float*)alloc((size_t)N * 4 * 4);
    float* adst1  = (float*)alloc((size_t)N * 4 * 4);
    float* H2     = (float*)alloc((size_t)N * 16 * 4);
    float* out2   = (float*)alloc((size_t)N * 16 * 4);
    float* asrc2  = (float*)alloc((size_t)N * 4);
    float* adst2  = (float*)alloc((size_t)N * 4);
    float* pooled = (float*)alloc((size_t)G * 16 * 4);
    int*   deg    = (int*)  alloc((size_t)N * 4);
    int*   cur    = (int*)  alloc((size_t)N * 4);
    int*   offp   = (int*)  alloc((size_t)(N + 1) * 4);
    int*   ecsr   = (int*)  alloc((size_t)E * 4);

    auto cdiv = [](long long a, long long b) { return (int)((a + b - 1) / b); };

    // ----- CSR build (shared by both layers) -----
    hipMemsetAsync(deg, 0, (size_t)N * 4, stream);
    hipMemsetAsync(cur, 0, (size_t)N * 4, stream);
    k_hist<<<cdiv(E, 256), 256, 0, stream>>>(dst, deg, E);
    k_scan<<<1, 1024, 0, stream>>>(deg, offp, N);
    k_scatter<<<cdiv(E, 256), 256, 0, stream>>>(src, dst, offp, cur, ecsr, E);

    // ----- layer 1 -----
    k_gemm1<<<cdiv(N, 2), 256, 0, stream>>>(x, W1, as1, ad1, H1, asrc1, adst1, N);
    k_agg1<<<cdiv(N, 4), 256, 0, stream>>>(H1, asrc1, adst1, offp, ecsr, out1, N);

    // ----- layer 2 -----
    k_gemm2<<<cdiv(N, 16), 256, 0, stream>>>(out1, b1, W2, as2, ad2, H2, asrc2, adst2, N);
    k_agg2<<<cdiv(N, 4), 256, 0, stream>>>(H2, asrc2, adst2, offp, ecsr, out2, N);

    // ----- pool + final linear -----
    k_pool<<<G, 256, 0, stream>>>(out2, b2, nid, pooled, N);
    k_final<<<cdiv((long long)G * 64, 256), 256, 0, stream>>>(pooled, Wf, bf, outp, G);
}

// Round 3
// 347.574 us; speedup vs baseline: 2.3450x; 1.4408x over previous
//
#include <hip/hip_runtime.h>
#include <hip/hip_bf16.h>

// ---------------- helpers ----------------

__device__ __forceinline__ float lrelu02(float x) { return x > 0.f ? x : 0.2f * x; }

// ---------------- layer 1 GEMM + logits ----------------
// Tiled: BM=64 rows x BN=128 cols (full) x BK=32. 256 thr, 8x4 micro-tile/thread.
// H1[n,128] = x[n,:] @ W1 ; asrc[n,h] = sum_c H1[n,h,c]*a_src[h,c] (likewise adst)
__global__ __launch_bounds__(256) void k_gemm1(
    const float* __restrict__ x, const float* __restrict__ W1,
    const float* __restrict__ a_src, const float* __restrict__ a_dst,
    float* __restrict__ H1, float* __restrict__ asrcv, float* __restrict__ adstv, int N)
{
    __shared__ float sA[32][68];    // x tile, transposed [k][m], pad 68 keeps 16B align
    __shared__ float sB[32][128];   // W tile [k][n]
    const int tid = threadIdx.x;
    const int m0 = (tid >> 5) * 8;  // 8 rows per thread
    const int n0 = (tid & 31) * 4;  // 4 cols per thread
    const int rowbase = blockIdx.x * 64;

    float acc[8][4];
#pragma unroll
    for (int i = 0; i < 8; ++i)
#pragma unroll
        for (int j = 0; j < 4; ++j) acc[i][j] = 0.f;

    const int am  = tid >> 2;       // staging: x row 0..63
    const int ak0 = (tid & 3) * 8;  // 8 consecutive k
    const int bk  = tid >> 3;       // staging: W row (k) 0..31
    const int bn0 = (tid & 7) * 16; // 16 consecutive n

    for (int kt = 0; kt < 128; kt += 32) {
        int grow = rowbase + am;
        const float* xp = x + (size_t)(grow < N ? grow : N - 1) * 128 + kt + ak0;
        float4 xa = *(const float4*)(xp);
        float4 xb = *(const float4*)(xp + 4);
        sA[ak0 + 0][am] = xa.x; sA[ak0 + 1][am] = xa.y;
        sA[ak0 + 2][am] = xa.z; sA[ak0 + 3][am] = xa.w;
        sA[ak0 + 4][am] = xb.x; sA[ak0 + 5][am] = xb.y;
        sA[ak0 + 6][am] = xb.z; sA[ak0 + 7][am] = xb.w;
        const float* wp = W1 + (size_t)(kt + bk) * 128 + bn0;
#pragma unroll
        for (int q = 0; q < 4; ++q)
            *(float4*)&sB[bk][bn0 + q * 4] = *(const float4*)(wp + q * 4);
        __syncthreads();
#pragma unroll
        for (int k = 0; k < 32; ++k) {
            float4 a0 = *(const float4*)&sA[k][m0];
            float4 a1 = *(const float4*)&sA[k][m0 + 4];
            float4 b  = *(const float4*)&sB[k][n0];
            float av[8] = {a0.x, a0.y, a0.z, a0.w, a1.x, a1.y, a1.z, a1.w};
            float bv[4] = {b.x, b.y, b.z, b.w};
#pragma unroll
            for (int i = 0; i < 8; ++i)
#pragma unroll
                for (int j = 0; j < 4; ++j)
                    acc[i][j] = fmaf(av[i], bv[j], acc[i][j]);
        }
        __syncthreads();
    }

    // epilogue: H1 writes + fused logits
    const int h = n0 >> 5;
    const float4 asv = *(const float4*)&a_src[n0];
    const float4 adv = *(const float4*)&a_dst[n0];
#pragma unroll
    for (int i = 0; i < 8; ++i) {
        int grow = rowbase + m0 + i;
        if (grow < N)
            *(float4*)&H1[(size_t)grow * 128 + n0] =
                make_float4(acc[i][0], acc[i][1], acc[i][2], acc[i][3]);
        float vs = acc[i][0]*asv.x + acc[i][1]*asv.y + acc[i][2]*asv.z + acc[i][3]*asv.w;
        float vd = acc[i][0]*adv.x + acc[i][1]*adv.y + acc[i][2]*adv.z + acc[i][3]*adv.w;
        vs += __shfl_xor(vs, 1); vd += __shfl_xor(vd, 1);
        vs += __shfl_xor(vs, 2); vd += __shfl_xor(vd, 2);
        vs += __shfl_xor(vs, 4); vd += __shfl_xor(vd, 4);
        if ((tid & 7) == 0 && grow < N) {
            asrcv[grow * 4 + h] = vs;
            adstv[grow * 4 + h] = vd;
        }
    }
}

// ---------------- layer 2 GEMM + logits (input = relu(out1 + b1)) ----------------
// 64 rows/block; X tile + all of W2 in LDS; 4 threads/row x 4 cols.
__global__ __launch_bounds__(256) void k_gemm2(
    const float* __restrict__ X, const float* __restrict__ b1,
    const float* __restrict__ W2, const float* __restrict__ a_src2, const float* __restrict__ a_dst2,
    float* __restrict__ H2, float* __restrict__ asrcv, float* __restrict__ adstv, int N)
{
    __shared__ float xs[64][132];
    __shared__ float ws[128][16];
    const int tid = threadIdx.x;
    const int rowbase = blockIdx.x * 64;
    {   // stage W2 (128x16)
        int k = tid >> 1, c0 = (tid & 1) * 8;
        *(float4*)&ws[k][c0]     = *(const float4*)&W2[k * 16 + c0];
        *(float4*)&ws[k][c0 + 4] = *(const float4*)&W2[k * 16 + c0 + 4];
    }
    {   // stage relu(X+b1) tile
        int r = tid >> 2, k0 = (tid & 3) * 32;
        int grow = rowbase + r;
        const float* xp = X + (size_t)(grow < N ? grow : N - 1) * 128 + k0;
#pragma unroll
        for (int q = 0; q < 8; ++q) {
            float4 v  = *(const float4*)(xp + q * 4);
            float4 bb = *(const float4*)&b1[k0 + q * 4];
            xs[r][k0 + q*4 + 0] = fmaxf(v.x + bb.x, 0.f);
            xs[r][k0 + q*4 + 1] = fmaxf(v.y + bb.y, 0.f);
            xs[r][k0 + q*4 + 2] = fmaxf(v.z + bb.z, 0.f);
            xs[r][k0 + q*4 + 3] = fmaxf(v.w + bb.w, 0.f);
        }
    }
    __syncthreads();
    const int r = tid >> 2, c0 = (tid & 3) * 4;
    float acc[4] = {0.f, 0.f, 0.f, 0.f};
#pragma unroll 16
    for (int k = 0; k < 128; ++k) {
        float xv = xs[r][k];
        float4 w = *(const float4*)&ws[k][c0];
        acc[0] = fmaf(xv, w.x, acc[0]);
        acc[1] = fmaf(xv, w.y, acc[1]);
        acc[2] = fmaf(xv, w.z, acc[2]);
        acc[3] = fmaf(xv, w.w, acc[3]);
    }
    int grow = rowbase + r;
    const float4 as4 = *(const float4*)&a_src2[c0];
    const float4 ad4 = *(const float4*)&a_dst2[c0];
    float vs = acc[0]*as4.x + acc[1]*as4.y + acc[2]*as4.z + acc[3]*as4.w;
    float vd = acc[0]*ad4.x + acc[1]*ad4.y + acc[2]*ad4.z + acc[3]*ad4.w;
    vs += __shfl_xor(vs, 1); vd += __shfl_xor(vd, 1);
    vs += __shfl_xor(vs, 2); vd += __shfl_xor(vd, 2);
    if (grow < N) {
        *(float4*)&H2[(size_t)grow * 16 + c0] = make_float4(acc[0], acc[1], acc[2], acc[3]);
        if ((tid & 3) == 0) { asrcv[grow] = vs; adstv[grow] = vd; }
    }
}

// ---------------- CSR build ----------------
__global__ __launch_bounds__(256) void k_hist(
    const int* __restrict__ dst, int* __restrict__ deg, int E)
{
    int i = blockIdx.x * 256 + threadIdx.x;
    if (i < E) atomicAdd(&deg[dst[i]], 1);
}

__global__ __launch_bounds__(1024) void k_scan(
    const int* __restrict__ deg, int* __restrict__ off, int N)
{
    __shared__ int wsum[16];
    __shared__ int carry_s;
    const int lane = threadIdx.x & 63, w = threadIdx.x >> 6;
    if (threadIdx.x == 0) carry_s = 0;
    __syncthreads();
    for (int base = 0; base < N; base += 1024) {
        int i = base + threadIdx.x;
        int v = (i < N) ? deg[i] : 0;
        int sc = v;
#pragma unroll
        for (int s = 1; s < 64; s <<= 1) {
            int t = __shfl_up(sc, s);
            if (lane >= s) sc += t;
        }
        if (lane == 63) wsum[w] = sc;
        __syncthreads();
        if (threadIdx.x < 16) {
            int t = wsum[threadIdx.x];
#pragma unroll
            for (int s = 1; s < 16; s <<= 1) {
                int u = __shfl_up(t, s);
                if ((int)threadIdx.x >= s) t += u;
            }
            wsum[threadIdx.x] = t;
        }
        __syncthreads();
        int carry = carry_s;
        int woff  = (w == 0) ? 0 : wsum[w - 1];
        if (i < N) off[i + 1] = carry + woff + sc;
        __syncthreads();
        if (threadIdx.x == 0) carry_s = carry + wsum[15];
        __syncthreads();
    }
    if (threadIdx.x == 0) off[0] = 0;
}

__global__ __launch_bounds__(256) void k_scatter(
    const int* __restrict__ src, const int* __restrict__ dst,
    const int* __restrict__ off, int* __restrict__ cur,
    int* __restrict__ ecsr, int E)
{
    int i = blockIdx.x * 256 + threadIdx.x;
    if (i >= E) return;
    int d = dst[i];
    int p = off[d] + atomicAdd(&cur[d], 1);
    ecsr[p] = src[i];
}

// ---------------- fused per-node softmax + aggregation ----------------
__global__ __launch_bounds__(256) void k_agg1(
    const float* __restrict__ H1, const float* __restrict__ asrc, const float* __restrict__ adst,
    const int* __restrict__ off, const int* __restrict__ ecsr,
    float* __restrict__ out, int N)
{
    const int w = threadIdx.x >> 6, lane = threadIdx.x & 63;
    const int n = blockIdx.x * 4 + w;
    if (n >= N) return;
    const int beg = off[n], deg = off[n + 1] - beg;

    const float4 ad4 = *(const float4*)&adst[n * 4];
    const float4 as4 = *(const float4*)&asrc[n * 4];
    const float ad[4] = { ad4.x, ad4.y, ad4.z, ad4.w };
    float vself[4] = { lrelu02(as4.x + ad4.x), lrelu02(as4.y + ad4.y),
                       lrelu02(as4.z + ad4.z), lrelu02(as4.w + ad4.w) };
    float m[4] = { vself[0], vself[1], vself[2], vself[3] };
    for (int j = lane; j < deg; j += 64) {
        int s = ecsr[beg + j];
        const float4 a = *(const float4*)&asrc[s * 4];
        m[0] = fmaxf(m[0], lrelu02(a.x + ad[0]));
        m[1] = fmaxf(m[1], lrelu02(a.y + ad[1]));
        m[2] = fmaxf(m[2], lrelu02(a.z + ad[2]));
        m[3] = fmaxf(m[3], lrelu02(a.w + ad[3]));
    }
#pragma unroll
    for (int xm = 32; xm >= 1; xm >>= 1) {
        m[0] = fmaxf(m[0], __shfl_xor(m[0], xm));
        m[1] = fmaxf(m[1], __shfl_xor(m[1], xm));
        m[2] = fmaxf(m[2], __shfl_xor(m[2], xm));
        m[3] = fmaxf(m[3], __shfl_xor(m[3], xm));
    }
    float ss[4] = { 0.f, 0.f, 0.f, 0.f };
    for (int j = lane; j < deg; j += 64) {
        int s = ecsr[beg + j];
        const float4 a = *(const float4*)&asrc[s * 4];
        ss[0] += __expf(lrelu02(a.x + ad[0]) - m[0]);
        ss[1] += __expf(lrelu02(a.y + ad[1]) - m[1]);
        ss[2] += __expf(lrelu02(a.z + ad[2]) - m[2]);
        ss[3] += __expf(lrelu02(a.w + ad[3]) - m[3]);
    }
#pragma unroll
    for (int xm = 32; xm >= 1; xm >>= 1) {
        ss[0] += __shfl_xor(ss[0], xm);
        ss[1] += __shfl_xor(ss[1], xm);
        ss[2] += __shfl_xor(ss[2], xm);
        ss[3] += __shfl_xor(ss[3], xm);
    }
    float inv[4], aself[4];
#pragma unroll
    for (int h = 0; h < 4; ++h) {
        float e = __expf(vself[h] - m[h]);
        inv[h]   = 1.f / (ss[h] + e + 1e-16f);
        aself[h] = e * inv[h];
    }
    const int c2 = lane * 2;
    const int h  = lane >> 4;
    const float mh = m[h], ih = inv[h], adh = ad[h];
    const float2 hself = *(const float2*)&H1[(size_t)n * 128 + c2];
    float accx = aself[h] * hself.x, accy = aself[h] * hself.y;
    int s = (deg > 0) ? ecsr[beg] : 0;
    for (int j = 0; j < deg; ++j) {
        int snext = (j + 1 < deg) ? ecsr[beg + j + 1] : 0;
        float a  = asrc[s * 4 + h];
        float2 v = *(const float2*)&H1[(size_t)s * 128 + c2];
        float al = __expf(lrelu02(a + adh) - mh) * ih;
        accx += al * v.x;
        accy += al * v.y;
        s = snext;
    }
    *(float2*)&out[(size_t)n * 128 + c2] = make_float2(accx, accy);
}

__global__ __launch_bounds__(256) void k_agg2(
    const float* __restrict__ H2, const float* __restrict__ asrc, const float* __restrict__ adst,
    const int* __restrict__ off, const int* __restrict__ ecsr,
    float* __restrict__ out, int N)
{
    const int w = threadIdx.x >> 6, lane = threadIdx.x & 63;
    const int n = blockIdx.x * 4 + w;
    if (n >= N) return;
    const int beg = off[n], deg = off[n + 1] - beg;

    const float adv = adst[n];
    const float vself = lrelu02(asrc[n] + adv);
    float m = vself;
    for (int j = lane; j < deg; j += 64)
        m = fmaxf(m, lrelu02(asrc[ecsr[beg + j]] + adv));
#pragma unroll
    for (int xm = 32; xm >= 1; xm >>= 1) m = fmaxf(m, __shfl_xor(m, xm));
    float ssum = 0.f;
    for (int j = lane; j < deg; j += 64)
        ssum += __expf(lrelu02(asrc[ecsr[beg + j]] + adv) - m);
#pragma unroll
    for (int xm = 32; xm >= 1; xm >>= 1) ssum += __shfl_xor(ssum, xm);
    float eself = __expf(vself - m);
    float inv = 1.f / (ssum + eself + 1e-16f);

    const int c = lane & 15, g = lane >> 4;
    float acc = (g == 0) ? (eself * inv) * H2[(size_t)n * 16 + c] : 0.f;
    for (int j = g; j < deg; j += 4) {
        int s = ecsr[beg + j];
        float al = __expf(lrelu02(asrc[s] + adv) - m) * inv;
        acc += al * H2[(size_t)s * 16 + c];
    }
    acc += __shfl_xor(acc, 16);
    acc += __shfl_xor(acc, 32);
    if (g == 0) out[(size_t)n * 16 + c] = acc;
}

// ---------------- pooling ----------------
__global__ __launch_bounds__(256) void k_pool(
    const float* __restrict__ out2, const float* __restrict__ b2,
    const int* __restrict__ nodeIDs, float* __restrict__ pooled, int N)
{
    int g = blockIdx.x;
    int lo = 0, hi = N;
    while (lo < hi) { int mid = (lo + hi) >> 1; if (nodeIDs[mid] < g) lo = mid + 1; else hi = mid; }
    int start = lo;
    lo = 0; hi = N;
    while (lo < hi) { int mid = (lo + hi) >> 1; if (nodeIDs[mid] < g + 1) lo = mid + 1; else hi = mid; }
    int end = lo;

    int c = threadIdx.x & 15, grp = threadIdx.x >> 4;
    float bc = b2[c];
    float acc = 0.f;
    for (int n = start + grp; n < end; n += 16)
        acc += fmaxf(out2[(size_t)n * 16 + c] + bc, 0.f);

    __shared__ float sd[256];
    sd[threadIdx.x] = acc;
    __syncthreads();
#pragma unroll
    for (int s = 8; s >= 1; s >>= 1) {
        if (grp < s) sd[threadIdx.x] += sd[(grp + s) * 16 + c];
        __syncthreads();
    }
    if (threadIdx.x < 16) {
        float cnt = (float)(end - start);
        pooled[g * 16 + threadIdx.x] = sd[threadIdx.x] / fmaxf(cnt, 1.f);
    }
}

// ---------------- final linear ----------------
__global__ __launch_bounds__(256) void k_final(
    const float* __restrict__ pooled, const float* __restrict__ Wf,
    const float* __restrict__ bf, float* __restrict__ outp, int G)
{
    int i = blockIdx.x * 256 + threadIdx.x;
    if (i >= G * 64) return;
    int g = i >> 6, o = i & 63;
    float acc = bf[o];
#pragma unroll
    for (int k = 0; k < 16; ++k)
        acc = fmaf(pooled[g * 16 + k], Wf[k * 64 + o], acc);
    outp[i] = acc;
}

// ---------------- launcher ----------------
extern "C" void kernel_launch(void* const* d_in, const int* in_sizes, int n_in,
                              void* d_out, int out_size, void* d_ws, size_t ws_size,
                              hipStream_t stream)
{
    const float* x   = (const float*)d_in[0];
    const int*   ei  = (const int*)  d_in[1];
    const int*   nid = (const int*)  d_in[3];
    const float* W1  = (const float*)d_in[4];
    const float* as1 = (const float*)d_in[5];
    const float* ad1 = (const float*)d_in[6];
    const float* b1  = (const float*)d_in[7];
    const float* W2  = (const float*)d_in[8];
    const float* as2 = (const float*)d_in[9];
    const float* ad2 = (const float*)d_in[10];
    const float* b2  = (const float*)d_in[11];
    const float* Wf  = (const float*)d_in[12];
    const float* bf  = (const float*)d_in[13];
    float* outp = (float*)d_out;

    const int N = in_sizes[0] / 128;
    const int E = in_sizes[1] / 2;
    const int G = out_size / 64;
    const int* src = ei;
    const int* dst = ei + E;

    char* ws = (char*)d_ws;
    size_t off_b = 0;
    auto alloc = [&](size_t bytes) -> char* {
        char* p = ws + off_b;
        off_b += (bytes + 255) & ~(size_t)255;
        return p;
    };

    float* H1     = (float*)alloc((size_t)N * 128 * 4);
    float* out1   = (float*)alloc((size_t)N * 128 * 4);
    float* asrc1  = (float*)alloc((size_t)N * 4 * 4);
    float* adst1  = (float*)alloc((size_t)N * 4 * 4);
    float* H2     = (float*)alloc((size_t)N * 16 * 4);
    float* out2   = (float*)alloc((size_t)N * 16 * 4);
    float* asrc2  = (float*)alloc((size_t)N * 4);
    float* adst2  = (float*)alloc((size_t)N * 4);
    float* pooled = (float*)alloc((size_t)G * 16 * 4);
    int*   deg    = (int*)  alloc((size_t)N * 4);
    int*   cur    = (int*)  alloc((size_t)N * 4);
    int*   offp   = (int*)  alloc((size_t)(N + 1) * 4);
    int*   ecsr   = (int*)  alloc((size_t)E * 4);

    auto cdiv = [](long long a, long long b) { return (int)((a + b - 1) / b); };

    // ----- CSR build (shared by both layers) -----
    hipMemsetAsync(deg, 0, (size_t)N * 4, stream);
    hipMemsetAsync(cur, 0, (size_t)N * 4, stream);
    k_hist<<<cdiv(E, 256), 256, 0, stream>>>(dst, deg, E);
    k_scan<<<1, 1024, 0, stream>>>(deg, offp, N);
    k_scatter<<<cdiv(E, 256), 256, 0, stream>>>(src, dst, offp, cur, ecsr, E);

    // ----- layer 1 -----
    k_gemm1<<<cdiv(N, 64), 256, 0, stream>>>(x, W1, as1, ad1, H1, asrc1, adst1, N);
    k_agg1<<<cdiv(N, 4), 256, 0, stream>>>(H1, asrc1, adst1, offp, ecsr, out1, N);

    // ----- layer 2 -----
    k_gemm2<<<cdiv(N, 64), 256, 0, stream>>>(out1, b1, W2, as2, ad2, H2, asrc2, adst2, N);
    k_agg2<<<cdiv(N, 4), 256, 0, stream>>>(H2, asrc2, adst2, offp, ecsr, out2, N);

    // ----- pool + final linear -----
    k_pool<<<G, 256, 0, stream>>>(out2, b2, nid, pooled, N);
    k_final<<<cdiv((long long)G * 64, 256), 256, 0, stream>>>(pooled, Wf, bf, outp, G);
}

// Round 4
// 262.091 us; speedup vs baseline: 3.1098x; 1.3262x over previous
//
#include <hip/hip_runtime.h>
#include <hip/hip_bf16.h>

// ---------------- helpers ----------------

__device__ __forceinline__ float lrelu02(float x) { return x > 0.f ? x : 0.2f * x; }

// round-to-nearest-even f32 -> bf16 bits
__device__ __forceinline__ unsigned short f2bf(float f) {
    unsigned b = __float_as_uint(f);
    return (unsigned short)((b + 0x7fffu + ((b >> 16) & 1u)) >> 16);
}
// unpack 2 bf16 from a uint: low ushort = elem0, high = elem1
__device__ __forceinline__ float bf_lo(unsigned u) { return __uint_as_float(u << 16); }
__device__ __forceinline__ float bf_hi(unsigned u) { return __uint_as_float(u & 0xffff0000u); }

// ---------------- layer 1 GEMM + logits ----------------
// BM=64 x BN=128 x BK=32, 256 thr, 8x4 micro-tile. Outputs H1 as bf16.
__global__ __launch_bounds__(256) void k_gemm1(
    const float* __restrict__ x, const float* __restrict__ W1,
    const float* __restrict__ a_src, const float* __restrict__ a_dst,
    unsigned short* __restrict__ H1b, float* __restrict__ asrcv, float* __restrict__ adstv, int N)
{
    __shared__ float sA[32][68];
    __shared__ float sB[32][128];
    const int tid = threadIdx.x;
    const int m0 = (tid >> 5) * 8;
    const int n0 = (tid & 31) * 4;
    const int rowbase = blockIdx.x * 64;

    float acc[8][4];
#pragma unroll
    for (int i = 0; i < 8; ++i)
#pragma unroll
        for (int j = 0; j < 4; ++j) acc[i][j] = 0.f;

    const int am  = tid >> 2;
    const int ak0 = (tid & 3) * 8;
    const int bk  = tid >> 3;
    const int bn0 = (tid & 7) * 16;

    for (int kt = 0; kt < 128; kt += 32) {
        int grow = rowbase + am;
        const float* xp = x + (size_t)(grow < N ? grow : N - 1) * 128 + kt + ak0;
        float4 xa = *(const float4*)(xp);
        float4 xb = *(const float4*)(xp + 4);
        sA[ak0 + 0][am] = xa.x; sA[ak0 + 1][am] = xa.y;
        sA[ak0 + 2][am] = xa.z; sA[ak0 + 3][am] = xa.w;
        sA[ak0 + 4][am] = xb.x; sA[ak0 + 5][am] = xb.y;
        sA[ak0 + 6][am] = xb.z; sA[ak0 + 7][am] = xb.w;
        const float* wp = W1 + (size_t)(kt + bk) * 128 + bn0;
#pragma unroll
        for (int q = 0; q < 4; ++q)
            *(float4*)&sB[bk][bn0 + q * 4] = *(const float4*)(wp + q * 4);
        __syncthreads();
#pragma unroll
        for (int k = 0; k < 32; ++k) {
            float4 a0 = *(const float4*)&sA[k][m0];
            float4 a1 = *(const float4*)&sA[k][m0 + 4];
            float4 b  = *(const float4*)&sB[k][n0];
            float av[8] = {a0.x, a0.y, a0.z, a0.w, a1.x, a1.y, a1.z, a1.w};
            float bv[4] = {b.x, b.y, b.z, b.w};
#pragma unroll
            for (int i = 0; i < 8; ++i)
#pragma unroll
                for (int j = 0; j < 4; ++j)
                    acc[i][j] = fmaf(av[i], bv[j], acc[i][j]);
        }
        __syncthreads();
    }

    const int h = n0 >> 5;
    const float4 asv = *(const float4*)&a_src[n0];
    const float4 adv = *(const float4*)&a_dst[n0];
#pragma unroll
    for (int i = 0; i < 8; ++i) {
        int grow = rowbase + m0 + i;
        if (grow < N) {
            uint2 p;
            p.x = (unsigned)f2bf(acc[i][0]) | ((unsigned)f2bf(acc[i][1]) << 16);
            p.y = (unsigned)f2bf(acc[i][2]) | ((unsigned)f2bf(acc[i][3]) << 16);
            *(uint2*)&H1b[(size_t)grow * 128 + n0] = p;
        }
        float vs = acc[i][0]*asv.x + acc[i][1]*asv.y + acc[i][2]*asv.z + acc[i][3]*asv.w;
        float vd = acc[i][0]*adv.x + acc[i][1]*adv.y + acc[i][2]*adv.z + acc[i][3]*adv.w;
        vs += __shfl_xor(vs, 1); vd += __shfl_xor(vd, 1);
        vs += __shfl_xor(vs, 2); vd += __shfl_xor(vd, 2);
        vs += __shfl_xor(vs, 4); vd += __shfl_xor(vd, 4);
        if ((tid & 7) == 0 && grow < N) {
            asrcv[grow * 4 + h] = vs;
            adstv[grow * 4 + h] = vd;
        }
    }
}

// ---------------- layer 2 GEMM + logits (input = relu(out1 + b1)) ----------------
__global__ __launch_bounds__(256) void k_gemm2(
    const float* __restrict__ X, const float* __restrict__ b1,
    const float* __restrict__ W2, const float* __restrict__ a_src2, const float* __restrict__ a_dst2,
    unsigned short* __restrict__ H2b, float* __restrict__ asrcv, float* __restrict__ adstv, int N)
{
    __shared__ float xs[64][132];
    __shared__ float ws[128][16];
    const int tid = threadIdx.x;
    const int rowbase = blockIdx.x * 64;
    {
        int k = tid >> 1, c0 = (tid & 1) * 8;
        *(float4*)&ws[k][c0]     = *(const float4*)&W2[k * 16 + c0];
        *(float4*)&ws[k][c0 + 4] = *(const float4*)&W2[k * 16 + c0 + 4];
    }
    {
        int r = tid >> 2, k0 = (tid & 3) * 32;
        int grow = rowbase + r;
        const float* xp = X + (size_t)(grow < N ? grow : N - 1) * 128 + k0;
#pragma unroll
        for (int q = 0; q < 8; ++q) {
            float4 v  = *(const float4*)(xp + q * 4);
            float4 bb = *(const float4*)&b1[k0 + q * 4];
            xs[r][k0 + q*4 + 0] = fmaxf(v.x + bb.x, 0.f);
            xs[r][k0 + q*4 + 1] = fmaxf(v.y + bb.y, 0.f);
            xs[r][k0 + q*4 + 2] = fmaxf(v.z + bb.z, 0.f);
            xs[r][k0 + q*4 + 3] = fmaxf(v.w + bb.w, 0.f);
        }
    }
    __syncthreads();
    const int r = tid >> 2, c0 = (tid & 3) * 4;
    float acc[4] = {0.f, 0.f, 0.f, 0.f};
#pragma unroll 16
    for (int k = 0; k < 128; ++k) {
        float xv = xs[r][k];
        float4 w = *(const float4*)&ws[k][c0];
        acc[0] = fmaf(xv, w.x, acc[0]);
        acc[1] = fmaf(xv, w.y, acc[1]);
        acc[2] = fmaf(xv, w.z, acc[2]);
        acc[3] = fmaf(xv, w.w, acc[3]);
    }
    int grow = rowbase + r;
    const float4 as4 = *(const float4*)&a_src2[c0];
    const float4 ad4 = *(const float4*)&a_dst2[c0];
    float vs = acc[0]*as4.x + acc[1]*as4.y + acc[2]*as4.z + acc[3]*as4.w;
    float vd = acc[0]*ad4.x + acc[1]*ad4.y + acc[2]*ad4.z + acc[3]*ad4.w;
    vs += __shfl_xor(vs, 1); vd += __shfl_xor(vd, 1);
    vs += __shfl_xor(vs, 2); vd += __shfl_xor(vd, 2);
    if (grow < N) {
        uint2 p;
        p.x = (unsigned)f2bf(acc[0]) | ((unsigned)f2bf(acc[1]) << 16);
        p.y = (unsigned)f2bf(acc[2]) | ((unsigned)f2bf(acc[3]) << 16);
        *(uint2*)&H2b[(size_t)grow * 16 + c0] = p;
        if ((tid & 3) == 0) { asrcv[grow] = vs; adstv[grow] = vd; }
    }
}

// ---------------- CSR build ----------------
__global__ __launch_bounds__(256) void k_hist(
    const int* __restrict__ dst, int* __restrict__ deg, int E)
{
    int i = blockIdx.x * 256 + threadIdx.x;
    if (i < E) atomicAdd(&deg[dst[i]], 1);
}

__global__ __launch_bounds__(1024) void k_scan(
    const int* __restrict__ deg, int* __restrict__ off, int N)
{
    __shared__ int wsum[16];
    __shared__ int carry_s;
    const int lane = threadIdx.x & 63, w = threadIdx.x >> 6;
    if (threadIdx.x == 0) carry_s = 0;
    __syncthreads();
    for (int base = 0; base < N; base += 1024) {
        int i = base + threadIdx.x;
        int v = (i < N) ? deg[i] : 0;
        int sc = v;
#pragma unroll
        for (int s = 1; s < 64; s <<= 1) {
            int t = __shfl_up(sc, s);
            if (lane >= s) sc += t;
        }
        if (lane == 63) wsum[w] = sc;
        __syncthreads();
        if (threadIdx.x < 16) {
            int t = wsum[threadIdx.x];
#pragma unroll
            for (int s = 1; s < 16; s <<= 1) {
                int u = __shfl_up(t, s);
                if ((int)threadIdx.x >= s) t += u;
            }
            wsum[threadIdx.x] = t;
        }
        __syncthreads();
        int carry = carry_s;
        int woff  = (w == 0) ? 0 : wsum[w - 1];
        if (i < N) off[i + 1] = carry + woff + sc;
        __syncthreads();
        if (threadIdx.x == 0) carry_s = carry + wsum[15];
        __syncthreads();
    }
    if (threadIdx.x == 0) off[0] = 0;
}

__global__ __launch_bounds__(256) void k_scatter(
    const int* __restrict__ src, const int* __restrict__ dst,
    const int* __restrict__ off, int* __restrict__ cur,
    int* __restrict__ ecsr, int E)
{
    int i = blockIdx.x * 256 + threadIdx.x;
    if (i >= E) return;
    int d = dst[i];
    int p = off[d] + atomicAdd(&cur[d], 1);
    ecsr[p] = src[i];
}

// ---------------- fused softmax + aggregation, layer 1 ----------------
// wave per node; no max pass (exp(v) direct); e broadcast via LDS;
// channel phase: 4 edge-groups x 16 lanes x 8 ch (bf16 H1).
__global__ __launch_bounds__(256) void k_agg1(
    const unsigned short* __restrict__ H1b, const float* __restrict__ asrc, const float* __restrict__ adst,
    const int* __restrict__ off, const int* __restrict__ ecsr,
    float* __restrict__ out, int N)
{
    __shared__ float sEs[4][64 * 4];
    __shared__ int   sSs[4][64];
    const int w = threadIdx.x >> 6, lane = threadIdx.x & 63;
    float* sE = sEs[w];
    int*   sS = sSs[w];
    const int n = blockIdx.x * 4 + w;
    if (n >= N) return;
    const int beg = off[n], deg = off[n + 1] - beg;

    const float4 ad4 = *(const float4*)&adst[n * 4];
    const float4 as4 = *(const float4*)&asrc[n * 4];
    // self terms
    float es0 = __expf(lrelu02(as4.x + ad4.x));
    float es1 = __expf(lrelu02(as4.y + ad4.y));
    float es2 = __expf(lrelu02(as4.z + ad4.z));
    float es3 = __expf(lrelu02(as4.w + ad4.w));
    float ssum0 = es0, ssum1 = es1, ssum2 = es2, ssum3 = es3; // lane0 carries self; others add edges

    // only lane 0 should seed the self term (each lane accumulates partials)
    if (lane != 0) { ssum0 = 0.f; ssum1 = 0.f; ssum2 = 0.f; ssum3 = 0.f; }

    const int g = lane >> 4, q = lane & 15;
    const int c0 = q * 8, h = q >> 2;
    float acc[8] = {0.f,0.f,0.f,0.f,0.f,0.f,0.f,0.f};

    for (int cb = 0; cb < deg; cb += 64) {
        int cnt = min(64, deg - cb);
        if (lane < cnt) {
            int s = ecsr[beg + cb + lane];
            sS[lane] = s;
            const float4 a = *(const float4*)&asrc[s * 4];
            float e0 = __expf(lrelu02(a.x + ad4.x));
            float e1 = __expf(lrelu02(a.y + ad4.y));
            float e2 = __expf(lrelu02(a.z + ad4.z));
            float e3 = __expf(lrelu02(a.w + ad4.w));
            ssum0 += e0; ssum1 += e1; ssum2 += e2; ssum3 += e3;
            sE[lane * 4 + 0] = e0; sE[lane * 4 + 1] = e1;
            sE[lane * 4 + 2] = e2; sE[lane * 4 + 3] = e3;
        }
        // same-wave lockstep: LDS writes visible to all lanes w/o barrier
        for (int j = g; j < cnt; j += 4) {
            int s = sS[j];
            float e = sE[j * 4 + h];
            uint4 u = *(const uint4*)&H1b[(size_t)s * 128 + c0];
            acc[0] = fmaf(e, bf_lo(u.x), acc[0]);
            acc[1] = fmaf(e, bf_hi(u.x), acc[1]);
            acc[2] = fmaf(e, bf_lo(u.y), acc[2]);
            acc[3] = fmaf(e, bf_hi(u.y), acc[3]);
            acc[4] = fmaf(e, bf_lo(u.z), acc[4]);
            acc[5] = fmaf(e, bf_hi(u.z), acc[5]);
            acc[6] = fmaf(e, bf_lo(u.w), acc[6]);
            acc[7] = fmaf(e, bf_hi(u.w), acc[7]);
        }
    }

#pragma unroll
    for (int xm = 32; xm >= 1; xm >>= 1) {
        ssum0 += __shfl_xor(ssum0, xm);
        ssum1 += __shfl_xor(ssum1, xm);
        ssum2 += __shfl_xor(ssum2, xm);
        ssum3 += __shfl_xor(ssum3, xm);
    }
#pragma unroll
    for (int k = 0; k < 8; ++k) {
        acc[k] += __shfl_xor(acc[k], 16);
        acc[k] += __shfl_xor(acc[k], 32);
    }
    if (g == 0) {
        float ssv = (h == 0) ? ssum0 : (h == 1) ? ssum1 : (h == 2) ? ssum2 : ssum3;
        float esv = (h == 0) ? es0   : (h == 1) ? es1   : (h == 2) ? es2   : es3;
        float inv = 1.f / (ssv + 1e-16f);
        uint4 u = *(const uint4*)&H1b[(size_t)n * 128 + c0];
        float o[8];
        o[0] = (acc[0] + esv * bf_lo(u.x)) * inv;
        o[1] = (acc[1] + esv * bf_hi(u.x)) * inv;
        o[2] = (acc[2] + esv * bf_lo(u.y)) * inv;
        o[3] = (acc[3] + esv * bf_hi(u.y)) * inv;
        o[4] = (acc[4] + esv * bf_lo(u.z)) * inv;
        o[5] = (acc[5] + esv * bf_hi(u.z)) * inv;
        o[6] = (acc[6] + esv * bf_lo(u.w)) * inv;
        o[7] = (acc[7] + esv * bf_hi(u.w)) * inv;
        *(float4*)&out[(size_t)n * 128 + c0]     = make_float4(o[0], o[1], o[2], o[3]);
        *(float4*)&out[(size_t)n * 128 + c0 + 4] = make_float4(o[4], o[5], o[6], o[7]);
    }
}

// ---------------- fused softmax + aggregation, layer 2 ----------------
// wave per node; 8 edge-groups x 8 lanes x 2 ch (bf16 H2).
__global__ __launch_bounds__(256) void k_agg2(
    const unsigned short* __restrict__ H2b, const float* __restrict__ asrc, const float* __restrict__ adst,
    const int* __restrict__ off, const int* __restrict__ ecsr,
    float* __restrict__ out, int N)
{
    __shared__ float sEs[4][64];
    __shared__ int   sSs[4][64];
    const int w = threadIdx.x >> 6, lane = threadIdx.x & 63;
    float* sE = sEs[w];
    int*   sS = sSs[w];
    const int n = blockIdx.x * 4 + w;
    if (n >= N) return;
    const int beg = off[n], deg = off[n + 1] - beg;

    const float adv = adst[n];
    float eself = __expf(lrelu02(asrc[n] + adv));
    float ssum = (lane == 0) ? eself : 0.f;

    const int g = lane >> 3, q = lane & 7;
    const int c0 = q * 2;
    float acc0 = 0.f, acc1 = 0.f;

    for (int cb = 0; cb < deg; cb += 64) {
        int cnt = min(64, deg - cb);
        if (lane < cnt) {
            int s = ecsr[beg + cb + lane];
            sS[lane] = s;
            float e = __expf(lrelu02(asrc[s] + adv));
            ssum += e;
            sE[lane] = e;
        }
        for (int j = g; j < cnt; j += 8) {
            int s = sS[j];
            float e = sE[j];
            unsigned u = *(const unsigned*)&H2b[(size_t)s * 16 + c0];
            acc0 = fmaf(e, bf_lo(u), acc0);
            acc1 = fmaf(e, bf_hi(u), acc1);
        }
    }
#pragma unroll
    for (int xm = 32; xm >= 1; xm >>= 1) ssum += __shfl_xor(ssum, xm);
    acc0 += __shfl_xor(acc0, 8);  acc1 += __shfl_xor(acc1, 8);
    acc0 += __shfl_xor(acc0, 16); acc1 += __shfl_xor(acc1, 16);
    acc0 += __shfl_xor(acc0, 32); acc1 += __shfl_xor(acc1, 32);
    if (g == 0) {
        float inv = 1.f / (ssum + 1e-16f);
        unsigned u = *(const unsigned*)&H2b[(size_t)n * 16 + c0];
        float2 o;
        o.x = (acc0 + eself * bf_lo(u)) * inv;
        o.y = (acc1 + eself * bf_hi(u)) * inv;
        *(float2*)&out[(size_t)n * 16 + c0] = o;
    }
}

// ---------------- pooling ----------------
__global__ __launch_bounds__(256) void k_pool(
    const float* __restrict__ out2, const float* __restrict__ b2,
    const int* __restrict__ nodeIDs, float* __restrict__ pooled, int N)
{
    int g = blockIdx.x;
    int lo = 0, hi = N;
    while (lo < hi) { int mid = (lo + hi) >> 1; if (nodeIDs[mid] < g) lo = mid + 1; else hi = mid; }
    int start = lo;
    lo = 0; hi = N;
    while (lo < hi) { int mid = (lo + hi) >> 1; if (nodeIDs[mid] < g + 1) lo = mid + 1; else hi = mid; }
    int end = lo;

    int c = threadIdx.x & 15, grp = threadIdx.x >> 4;
    float bc = b2[c];
    float acc = 0.f;
    for (int n = start + grp; n < end; n += 16)
        acc += fmaxf(out2[(size_t)n * 16 + c] + bc, 0.f);

    __shared__ float sd[256];
    sd[threadIdx.x] = acc;
    __syncthreads();
#pragma unroll
    for (int s = 8; s >= 1; s >>= 1) {
        if (grp < s) sd[threadIdx.x] += sd[(grp + s) * 16 + c];
        __syncthreads();
    }
    if (threadIdx.x < 16) {
        float cnt = (float)(end - start);
        pooled[g * 16 + threadIdx.x] = sd[threadIdx.x] / fmaxf(cnt, 1.f);
    }
}

// ---------------- final linear ----------------
__global__ __launch_bounds__(256) void k_final(
    const float* __restrict__ pooled, const float* __restrict__ Wf,
    const float* __restrict__ bf, float* __restrict__ outp, int G)
{
    int i = blockIdx.x * 256 + threadIdx.x;
    if (i >= G * 64) return;
    int g = i >> 6, o = i & 63;
    float acc = bf[o];
#pragma unroll
    for (int k = 0; k < 16; ++k)
        acc = fmaf(pooled[g * 16 + k], Wf[k * 64 + o], acc);
    outp[i] = acc;
}

// ---------------- launcher ----------------
extern "C" void kernel_launch(void* const* d_in, const int* in_sizes, int n_in,
                              void* d_out, int out_size, void* d_ws, size_t ws_size,
                              hipStream_t stream)
{
    const float* x   = (const float*)d_in[0];
    const int*   ei  = (const int*)  d_in[1];
    const int*   nid = (const int*)  d_in[3];
    const float* W1  = (const float*)d_in[4];
    const float* as1 = (const float*)d_in[5];
    const float* ad1 = (const float*)d_in[6];
    const float* b1  = (const float*)d_in[7];
    const float* W2  = (const float*)d_in[8];
    const float* as2 = (const float*)d_in[9];
    const float* ad2 = (const float*)d_in[10];
    const float* b2  = (const float*)d_in[11];
    const float* Wf  = (const float*)d_in[12];
    const float* bf  = (const float*)d_in[13];
    float* outp = (float*)d_out;

    const int N = in_sizes[0] / 128;
    const int E = in_sizes[1] / 2;
    const int G = out_size / 64;
    const int* src = ei;
    const int* dst = ei + E;

    char* ws = (char*)d_ws;
    size_t off_b = 0;
    auto alloc = [&](size_t bytes) -> char* {
        char* p = ws + off_b;
        off_b += (bytes + 255) & ~(size_t)255;
        return p;
    };

    unsigned short* H1b  = (unsigned short*)alloc((size_t)N * 128 * 2);
    unsigned short* H2b  = (unsigned short*)alloc((size_t)N * 16 * 2);
    float* out1   = (float*)alloc((size_t)N * 128 * 4);
    float* asrc1  = (float*)alloc((size_t)N * 4 * 4);
    float* adst1  = (float*)alloc((size_t)N * 4 * 4);
    float* out2   = (float*)alloc((size_t)N * 16 * 4);
    float* asrc2  = (float*)alloc((size_t)N * 4);
    float* adst2  = (float*)alloc((size_t)N * 4);
    float* pooled = (float*)alloc((size_t)G * 16 * 4);
    int*   deg    = (int*)  alloc((size_t)N * 4);
    int*   cur    = (int*)  alloc((size_t)N * 4);
    int*   offp   = (int*)  alloc((size_t)(N + 1) * 4);
    int*   ecsr   = (int*)  alloc((size_t)E * 4);

    auto cdiv = [](long long a, long long b) { return (int)((a + b - 1) / b); };

    // ----- CSR build (shared by both layers) -----
    hipMemsetAsync(deg, 0, (size_t)N * 4, stream);
    hipMemsetAsync(cur, 0, (size_t)N * 4, stream);
    k_hist<<<cdiv(E, 256), 256, 0, stream>>>(dst, deg, E);
    k_scan<<<1, 1024, 0, stream>>>(deg, offp, N);
    k_scatter<<<cdiv(E, 256), 256, 0, stream>>>(src, dst, offp, cur, ecsr, E);

    // ----- layer 1 -----
    k_gemm1<<<cdiv(N, 64), 256, 0, stream>>>(x, W1, as1, ad1, H1b, asrc1, adst1, N);
    k_agg1<<<cdiv(N, 4), 256, 0, stream>>>(H1b, asrc1, adst1, offp, ecsr, out1, N);

    // ----- layer 2 -----
    k_gemm2<<<cdiv(N, 64), 256, 0, stream>>>(out1, b1, W2, as2, ad2, H2b, asrc2, adst2, N);
    k_agg2<<<cdiv(N, 4), 256, 0, stream>>>(H2b, asrc2, adst2, offp, ecsr, out2, N);

    // ----- pool + final linear -----
    k_pool<<<G, 256, 0, stream>>>(out2, b2, nid, pooled, N);
    k_final<<<cdiv((long long)G * 64, 256), 256, 0, stream>>>(pooled, Wf, bf, outp, G);
}

// Round 5
// 227.647 us; speedup vs baseline: 3.5803x; 1.1513x over previous
//
#include <hip/hip_runtime.h>
#include <hip/hip_bf16.h>

// ---------------- helpers ----------------

__device__ __forceinline__ float lrelu02(float x) { return x > 0.f ? x : 0.2f * x; }

// round-to-nearest-even f32 -> bf16 bits
__device__ __forceinline__ unsigned short f2bf(float f) {
    unsigned b = __float_as_uint(f);
    return (unsigned short)((b + 0x7fffu + ((b >> 16) & 1u)) >> 16);
}
__device__ __forceinline__ float bf_lo(unsigned u) { return __uint_as_float(u << 16); }
__device__ __forceinline__ float bf_hi(unsigned u) { return __uint_as_float(u & 0xffff0000u); }

// ---------------- layer 1 GEMM + logits, with fused dst-histogram ----------------
// Blocks [0,GB): BM=64 x BN=128 x BK=32 GEMM tile (8x4 micro-tile/thread), bf16 H1 out.
// Blocks [GB,gridDim): grid-stride histogram of dst -> deg (hides the hist pass).
__global__ __launch_bounds__(256) void k_gemm1h(
    const float* __restrict__ x, const float* __restrict__ W1,
    const float* __restrict__ a_src, const float* __restrict__ a_dst,
    unsigned short* __restrict__ H1b, float* __restrict__ asrcv, float* __restrict__ adstv, int N,
    const int* __restrict__ dst, int* __restrict__ deg, int E, int GB)
{
    if ((int)blockIdx.x >= GB) {
        const int nb = gridDim.x - GB;
        const int bi = blockIdx.x - GB;
        for (int i = bi * 256 + threadIdx.x; i < E; i += nb * 256)
            atomicAdd(&deg[dst[i]], 1);
        return;
    }

    __shared__ float sA[32][68];
    __shared__ float sB[32][128];
    const int tid = threadIdx.x;
    const int m0 = (tid >> 5) * 8;
    const int n0 = (tid & 31) * 4;
    const int rowbase = blockIdx.x * 64;

    float acc[8][4];
#pragma unroll
    for (int i = 0; i < 8; ++i)
#pragma unroll
        for (int j = 0; j < 4; ++j) acc[i][j] = 0.f;

    const int am  = tid >> 2;
    const int ak0 = (tid & 3) * 8;
    const int bk  = tid >> 3;
    const int bn0 = (tid & 7) * 16;

    for (int kt = 0; kt < 128; kt += 32) {
        int grow = rowbase + am;
        const float* xp = x + (size_t)(grow < N ? grow : N - 1) * 128 + kt + ak0;
        float4 xa = *(const float4*)(xp);
        float4 xb = *(const float4*)(xp + 4);
        sA[ak0 + 0][am] = xa.x; sA[ak0 + 1][am] = xa.y;
        sA[ak0 + 2][am] = xa.z; sA[ak0 + 3][am] = xa.w;
        sA[ak0 + 4][am] = xb.x; sA[ak0 + 5][am] = xb.y;
        sA[ak0 + 6][am] = xb.z; sA[ak0 + 7][am] = xb.w;
        const float* wp = W1 + (size_t)(kt + bk) * 128 + bn0;
#pragma unroll
        for (int q = 0; q < 4; ++q)
            *(float4*)&sB[bk][bn0 + q * 4] = *(const float4*)(wp + q * 4);
        __syncthreads();
#pragma unroll
        for (int k = 0; k < 32; ++k) {
            float4 a0 = *(const float4*)&sA[k][m0];
            float4 a1 = *(const float4*)&sA[k][m0 + 4];
            float4 b  = *(const float4*)&sB[k][n0];
            float av[8] = {a0.x, a0.y, a0.z, a0.w, a1.x, a1.y, a1.z, a1.w};
            float bv[4] = {b.x, b.y, b.z, b.w};
#pragma unroll
            for (int i = 0; i < 8; ++i)
#pragma unroll
                for (int j = 0; j < 4; ++j)
                    acc[i][j] = fmaf(av[i], bv[j], acc[i][j]);
        }
        __syncthreads();
    }

    const int h = n0 >> 5;
    const float4 asv = *(const float4*)&a_src[n0];
    const float4 adv = *(const float4*)&a_dst[n0];
#pragma unroll
    for (int i = 0; i < 8; ++i) {
        int grow = rowbase + m0 + i;
        if (grow < N) {
            uint2 p;
            p.x = (unsigned)f2bf(acc[i][0]) | ((unsigned)f2bf(acc[i][1]) << 16);
            p.y = (unsigned)f2bf(acc[i][2]) | ((unsigned)f2bf(acc[i][3]) << 16);
            *(uint2*)&H1b[(size_t)grow * 128 + n0] = p;
        }
        float vs = acc[i][0]*asv.x + acc[i][1]*asv.y + acc[i][2]*asv.z + acc[i][3]*asv.w;
        float vd = acc[i][0]*adv.x + acc[i][1]*adv.y + acc[i][2]*adv.z + acc[i][3]*adv.w;
        vs += __shfl_xor(vs, 1); vd += __shfl_xor(vd, 1);
        vs += __shfl_xor(vs, 2); vd += __shfl_xor(vd, 2);
        vs += __shfl_xor(vs, 4); vd += __shfl_xor(vd, 4);
        if ((tid & 7) == 0 && grow < N) {
            asrcv[grow * 4 + h] = vs;
            adstv[grow * 4 + h] = vd;
        }
    }
}

// ---------------- layer 2 GEMM + logits (input = relu(out1 + b1)) ----------------
__global__ __launch_bounds__(256) void k_gemm2(
    const float* __restrict__ X, const float* __restrict__ b1,
    const float* __restrict__ W2, const float* __restrict__ a_src2, const float* __restrict__ a_dst2,
    unsigned short* __restrict__ H2b, float* __restrict__ asrcv, float* __restrict__ adstv, int N)
{
    __shared__ float xs[64][132];
    __shared__ float ws[128][16];
    const int tid = threadIdx.x;
    const int rowbase = blockIdx.x * 64;
    {
        int k = tid >> 1, c0 = (tid & 1) * 8;
        *(float4*)&ws[k][c0]     = *(const float4*)&W2[k * 16 + c0];
        *(float4*)&ws[k][c0 + 4] = *(const float4*)&W2[k * 16 + c0 + 4];
    }
    {
        int r = tid >> 2, k0 = (tid & 3) * 32;
        int grow = rowbase + r;
        const float* xp = X + (size_t)(grow < N ? grow : N - 1) * 128 + k0;
#pragma unroll
        for (int q = 0; q < 8; ++q) {
            float4 v  = *(const float4*)(xp + q * 4);
            float4 bb = *(const float4*)&b1[k0 + q * 4];
            xs[r][k0 + q*4 + 0] = fmaxf(v.x + bb.x, 0.f);
            xs[r][k0 + q*4 + 1] = fmaxf(v.y + bb.y, 0.f);
            xs[r][k0 + q*4 + 2] = fmaxf(v.z + bb.z, 0.f);
            xs[r][k0 + q*4 + 3] = fmaxf(v.w + bb.w, 0.f);
        }
    }
    __syncthreads();
    const int r = tid >> 2, c0 = (tid & 3) * 4;
    float acc[4] = {0.f, 0.f, 0.f, 0.f};
#pragma unroll 16
    for (int k = 0; k < 128; ++k) {
        float xv = xs[r][k];
        float4 w = *(const float4*)&ws[k][c0];
        acc[0] = fmaf(xv, w.x, acc[0]);
        acc[1] = fmaf(xv, w.y, acc[1]);
        acc[2] = fmaf(xv, w.z, acc[2]);
        acc[3] = fmaf(xv, w.w, acc[3]);
    }
    int grow = rowbase + r;
    const float4 as4 = *(const float4*)&a_src2[c0];
    const float4 ad4 = *(const float4*)&a_dst2[c0];
    float vs = acc[0]*as4.x + acc[1]*as4.y + acc[2]*as4.z + acc[3]*as4.w;
    float vd = acc[0]*ad4.x + acc[1]*ad4.y + acc[2]*ad4.z + acc[3]*ad4.w;
    vs += __shfl_xor(vs, 1); vd += __shfl_xor(vd, 1);
    vs += __shfl_xor(vs, 2); vd += __shfl_xor(vd, 2);
    if (grow < N) {
        uint2 p;
        p.x = (unsigned)f2bf(acc[0]) | ((unsigned)f2bf(acc[1]) << 16);
        p.y = (unsigned)f2bf(acc[2]) | ((unsigned)f2bf(acc[3]) << 16);
        *(uint2*)&H2b[(size_t)grow * 16 + c0] = p;
        if ((tid & 3) == 0) { asrcv[grow] = vs; adstv[grow] = vd; }
    }
}

// ---------------- CSR scan (also emits cur = exclusive prefix) ----------------
__global__ __launch_bounds__(1024) void k_scan(
    const int* __restrict__ deg, int* __restrict__ off, int* __restrict__ cur, int N)
{
    __shared__ int wsum[16];
    __shared__ int carry_s;
    const int lane = threadIdx.x & 63, w = threadIdx.x >> 6;
    if (threadIdx.x == 0) carry_s = 0;
    __syncthreads();
    for (int base = 0; base < N; base += 1024) {
        int i = base + threadIdx.x;
        int v = (i < N) ? deg[i] : 0;
        int sc = v;
#pragma unroll
        for (int s = 1; s < 64; s <<= 1) {
            int t = __shfl_up(sc, s);
            if (lane >= s) sc += t;
        }
        if (lane == 63) wsum[w] = sc;
        __syncthreads();
        if (threadIdx.x < 16) {
            int t = wsum[threadIdx.x];
#pragma unroll
            for (int s = 1; s < 16; s <<= 1) {
                int u = __shfl_up(t, s);
                if ((int)threadIdx.x >= s) t += u;
            }
            wsum[threadIdx.x] = t;
        }
        __syncthreads();
        int carry = carry_s;
        int woff  = (w == 0) ? 0 : wsum[w - 1];
        if (i < N) {
            int incl = carry + woff + sc;
            off[i + 1] = incl;
            cur[i] = incl - v;   // exclusive prefix
        }
        __syncthreads();
        if (threadIdx.x == 0) carry_s = carry + wsum[15];
        __syncthreads();
    }
    if (threadIdx.x == 0) off[0] = 0;
}

// ---------------- XCD-partitioned scatter ----------------
// Blocks with blockIdx&7 == g own dst slice g (blockIdx%8 -> XCD round-robin
// heuristic): each XCD writes a private ~200KB ecsr window -> L2-local lines.
// Perf heuristic only; correctness independent of the actual XCD mapping.
__global__ __launch_bounds__(256) void k_scatterx(
    const int* __restrict__ src, const int* __restrict__ dst,
    int* __restrict__ cur, unsigned short* __restrict__ ecsr, int E, int N)
{
    const int g  = blockIdx.x & 7;
    const int lo = (int)(((long long)N * g) >> 3);
    const int hi = (int)(((long long)N * (g + 1)) >> 3);
    const int nb = gridDim.x >> 3;
    const int bi = blockIdx.x >> 3;
    for (int i = bi * 256 + threadIdx.x; i < E; i += nb * 256) {
        int d = dst[i];
        if (d >= lo && d < hi) {
            int p = atomicAdd(&cur[d], 1);
            ecsr[p] = (unsigned short)src[i];
        }
    }
}

// ---------------- fused softmax + aggregation, layer 1 ----------------
__global__ __launch_bounds__(256) void k_agg1(
    const unsigned short* __restrict__ H1b, const float* __restrict__ asrc, const float* __restrict__ adst,
    const int* __restrict__ off, const unsigned short* __restrict__ ecsr,
    float* __restrict__ out, int N)
{
    __shared__ float sEs[4][64 * 4];
    __shared__ int   sSs[4][64];
    const int w = threadIdx.x >> 6, lane = threadIdx.x & 63;
    float* sE = sEs[w];
    int*   sS = sSs[w];
    const int n = blockIdx.x * 4 + w;
    if (n >= N) return;
    const int beg = off[n], deg = off[n + 1] - beg;

    const float4 ad4 = *(const float4*)&adst[n * 4];
    const float4 as4 = *(const float4*)&asrc[n * 4];
    float es0 = __expf(lrelu02(as4.x + ad4.x));
    float es1 = __expf(lrelu02(as4.y + ad4.y));
    float es2 = __expf(lrelu02(as4.z + ad4.z));
    float es3 = __expf(lrelu02(as4.w + ad4.w));
    float ssum0 = es0, ssum1 = es1, ssum2 = es2, ssum3 = es3;
    if (lane != 0) { ssum0 = 0.f; ssum1 = 0.f; ssum2 = 0.f; ssum3 = 0.f; }

    const int g = lane >> 4, q = lane & 15;
    const int c0 = q * 8, h = q >> 2;
    float acc[8] = {0.f,0.f,0.f,0.f,0.f,0.f,0.f,0.f};

    for (int cb = 0; cb < deg; cb += 64) {
        int cnt = min(64, deg - cb);
        if (lane < cnt) {
            int s = (int)ecsr[beg + cb + lane];
            sS[lane] = s;
            const float4 a = *(const float4*)&asrc[s * 4];
            float e0 = __expf(lrelu02(a.x + ad4.x));
            float e1 = __expf(lrelu02(a.y + ad4.y));
            float e2 = __expf(lrelu02(a.z + ad4.z));
            float e3 = __expf(lrelu02(a.w + ad4.w));
            ssum0 += e0; ssum1 += e1; ssum2 += e2; ssum3 += e3;
            sE[lane * 4 + 0] = e0; sE[lane * 4 + 1] = e1;
            sE[lane * 4 + 2] = e2; sE[lane * 4 + 3] = e3;
        }
        for (int j = g; j < cnt; j += 4) {
            int s = sS[j];
            float e = sE[j * 4 + h];
            uint4 u = *(const uint4*)&H1b[(size_t)s * 128 + c0];
            acc[0] = fmaf(e, bf_lo(u.x), acc[0]);
            acc[1] = fmaf(e, bf_hi(u.x), acc[1]);
            acc[2] = fmaf(e, bf_lo(u.y), acc[2]);
            acc[3] = fmaf(e, bf_hi(u.y), acc[3]);
            acc[4] = fmaf(e, bf_lo(u.z), acc[4]);
            acc[5] = fmaf(e, bf_hi(u.z), acc[5]);
            acc[6] = fmaf(e, bf_lo(u.w), acc[6]);
            acc[7] = fmaf(e, bf_hi(u.w), acc[7]);
        }
    }

#pragma unroll
    for (int xm = 32; xm >= 1; xm >>= 1) {
        ssum0 += __shfl_xor(ssum0, xm);
        ssum1 += __shfl_xor(ssum1, xm);
        ssum2 += __shfl_xor(ssum2, xm);
        ssum3 += __shfl_xor(ssum3, xm);
    }
#pragma unroll
    for (int k = 0; k < 8; ++k) {
        acc[k] += __shfl_xor(acc[k], 16);
        acc[k] += __shfl_xor(acc[k], 32);
    }
    if (g == 0) {
        float ssv = (h == 0) ? ssum0 : (h == 1) ? ssum1 : (h == 2) ? ssum2 : ssum3;
        float esv = (h == 0) ? es0   : (h == 1) ? es1   : (h == 2) ? es2   : es3;
        float inv = 1.f / (ssv + 1e-16f);
        uint4 u = *(const uint4*)&H1b[(size_t)n * 128 + c0];
        float o[8];
        o[0] = (acc[0] + esv * bf_lo(u.x)) * inv;
        o[1] = (acc[1] + esv * bf_hi(u.x)) * inv;
        o[2] = (acc[2] + esv * bf_lo(u.y)) * inv;
        o[3] = (acc[3] + esv * bf_hi(u.y)) * inv;
        o[4] = (acc[4] + esv * bf_lo(u.z)) * inv;
        o[5] = (acc[5] + esv * bf_hi(u.z)) * inv;
        o[6] = (acc[6] + esv * bf_lo(u.w)) * inv;
        o[7] = (acc[7] + esv * bf_hi(u.w)) * inv;
        *(float4*)&out[(size_t)n * 128 + c0]     = make_float4(o[0], o[1], o[2], o[3]);
        *(float4*)&out[(size_t)n * 128 + c0 + 4] = make_float4(o[4], o[5], o[6], o[7]);
    }
}

// ---------------- fused softmax + aggregation, layer 2 ----------------
__global__ __launch_bounds__(256) void k_agg2(
    const unsigned short* __restrict__ H2b, const float* __restrict__ asrc, const float* __restrict__ adst,
    const int* __restrict__ off, const unsigned short* __restrict__ ecsr,
    float* __restrict__ out, int N)
{
    __shared__ float sEs[4][64];
    __shared__ int   sSs[4][64];
    const int w = threadIdx.x >> 6, lane = threadIdx.x & 63;
    float* sE = sEs[w];
    int*   sS = sSs[w];
    const int n = blockIdx.x * 4 + w;
    if (n >= N) return;
    const int beg = off[n], deg = off[n + 1] - beg;

    const float adv = adst[n];
    float eself = __expf(lrelu02(asrc[n] + adv));
    float ssum = (lane == 0) ? eself : 0.f;

    const int g = lane >> 3, q = lane & 7;
    const int c0 = q * 2;
    float acc0 = 0.f, acc1 = 0.f;

    for (int cb = 0; cb < deg; cb += 64) {
        int cnt = min(64, deg - cb);
        if (lane < cnt) {
            int s = (int)ecsr[beg + cb + lane];
            sS[lane] = s;
            float e = __expf(lrelu02(asrc[s] + adv));
            ssum += e;
            sE[lane] = e;
        }
        for (int j = g; j < cnt; j += 8) {
            int s = sS[j];
            float e = sE[j];
            unsigned u = *(const unsigned*)&H2b[(size_t)s * 16 + c0];
            acc0 = fmaf(e, bf_lo(u), acc0);
            acc1 = fmaf(e, bf_hi(u), acc1);
        }
    }
#pragma unroll
    for (int xm = 32; xm >= 1; xm >>= 1) ssum += __shfl_xor(ssum, xm);
    acc0 += __shfl_xor(acc0, 8);  acc1 += __shfl_xor(acc1, 8);
    acc0 += __shfl_xor(acc0, 16); acc1 += __shfl_xor(acc1, 16);
    acc0 += __shfl_xor(acc0, 32); acc1 += __shfl_xor(acc1, 32);
    if (g == 0) {
        float inv = 1.f / (ssum + 1e-16f);
        unsigned u = *(const unsigned*)&H2b[(size_t)n * 16 + c0];
        float2 o;
        o.x = (acc0 + eself * bf_lo(u)) * inv;
        o.y = (acc1 + eself * bf_hi(u)) * inv;
        *(float2*)&out[(size_t)n * 16 + c0] = o;
    }
}

// ---------------- pooling + final linear (fused) ----------------
__global__ __launch_bounds__(256) void k_poolfinal(
    const float* __restrict__ out2, const float* __restrict__ b2,
    const int* __restrict__ nodeIDs, const float* __restrict__ Wf,
    const float* __restrict__ bf, float* __restrict__ outp, int N)
{
    int g = blockIdx.x;
    int lo = 0, hi = N;
    while (lo < hi) { int mid = (lo + hi) >> 1; if (nodeIDs[mid] < g) lo = mid + 1; else hi = mid; }
    int start = lo;
    lo = 0; hi = N;
    while (lo < hi) { int mid = (lo + hi) >> 1; if (nodeIDs[mid] < g + 1) lo = mid + 1; else hi = mid; }
    int end = lo;

    int c = threadIdx.x & 15, grp = threadIdx.x >> 4;
    float bc = b2[c];
    float acc = 0.f;
    for (int n = start + grp; n < end; n += 16)
        acc += fmaxf(out2[(size_t)n * 16 + c] + bc, 0.f);

    __shared__ float sd[256];
    __shared__ float p16[16];
    sd[threadIdx.x] = acc;
    __syncthreads();
#pragma unroll
    for (int s = 8; s >= 1; s >>= 1) {
        if (grp < s) sd[threadIdx.x] += sd[(grp + s) * 16 + c];
        __syncthreads();
    }
    if (threadIdx.x < 16) {
        float cnt = (float)(end - start);
        p16[threadIdx.x] = sd[threadIdx.x] / fmaxf(cnt, 1.f);
    }
    __syncthreads();
    if (threadIdx.x < 64) {
        int o = threadIdx.x;
        float a = bf[o];
#pragma unroll
        for (int k = 0; k < 16; ++k)
            a = fmaf(p16[k], Wf[k * 64 + o], a);
        outp[(size_t)g * 64 + o] = a;
    }
}

// ---------------- launcher ----------------
extern "C" void kernel_launch(void* const* d_in, const int* in_sizes, int n_in,
                              void* d_out, int out_size, void* d_ws, size_t ws_size,
                              hipStream_t stream)
{
    const float* x   = (const float*)d_in[0];
    const int*   ei  = (const int*)  d_in[1];
    const int*   nid = (const int*)  d_in[3];
    const float* W1  = (const float*)d_in[4];
    const float* as1 = (const float*)d_in[5];
    const float* ad1 = (const float*)d_in[6];
    const float* b1  = (const float*)d_in[7];
    const float* W2  = (const float*)d_in[8];
    const float* as2 = (const float*)d_in[9];
    const float* ad2 = (const float*)d_in[10];
    const float* b2  = (const float*)d_in[11];
    const float* Wf  = (const float*)d_in[12];
    const float* bf  = (const float*)d_in[13];
    float* outp = (float*)d_out;

    const int N = in_sizes[0] / 128;
    const int E = in_sizes[1] / 2;
    const int* src = ei;
    const int* dst = ei + E;

    char* ws = (char*)d_ws;
    size_t off_b = 0;
    auto alloc = [&](size_t bytes) -> char* {
        char* p = ws + off_b;
        off_b += (bytes + 255) & ~(size_t)255;
        return p;
    };

    unsigned short* H1b  = (unsigned short*)alloc((size_t)N * 128 * 2);
    unsigned short* H2b  = (unsigned short*)alloc((size_t)N * 16 * 2);
    unsigned short* ecsr = (unsigned short*)alloc((size_t)E * 2);
    float* out1   = (float*)alloc((size_t)N * 128 * 4);
    float* asrc1  = (float*)alloc((size_t)N * 4 * 4);
    float* adst1  = (float*)alloc((size_t)N * 4 * 4);
    float* out2   = (float*)alloc((size_t)N * 16 * 4);
    float* asrc2  = (float*)alloc((size_t)N * 4);
    float* adst2  = (float*)alloc((size_t)N * 4);
    int*   deg    = (int*)  alloc((size_t)N * 4);
    int*   cur    = (int*)  alloc((size_t)N * 4);
    int*   offp   = (int*)  alloc((size_t)(N + 1) * 4);

    auto cdiv = [](long long a, long long b) { return (int)((a + b - 1) / b); };

    const int GB = cdiv(N, 64);            // gemm1 tile blocks

    // deg must start at zero (hist accumulates into it)
    hipMemsetAsync(deg, 0, (size_t)N * 4, stream);

    // ----- layer 1 GEMM + hidden histogram -----
    k_gemm1h<<<GB + 256, 256, 0, stream>>>(x, W1, as1, ad1, H1b, asrc1, adst1, N,
                                           dst, deg, E, GB);
    // ----- CSR: scan (emits off and cur), XCD-partitioned scatter -----
    k_scan<<<1, 1024, 0, stream>>>(deg, offp, cur, N);
    k_scatterx<<<1024, 256, 0, stream>>>(src, dst, cur, ecsr, E, N);

    // ----- layer 1 aggregation -----
    k_agg1<<<cdiv(N, 4), 256, 0, stream>>>(H1b, asrc1, adst1, offp, ecsr, out1, N);

    // ----- layer 2 -----
    k_gemm2<<<cdiv(N, 64), 256, 0, stream>>>(out1, b1, W2, as2, ad2, H2b, asrc2, adst2, N);
    k_agg2<<<cdiv(N, 4), 256, 0, stream>>>(H2b, asrc2, adst2, offp, ecsr, out2, N);

    // ----- pool + final linear (fused) -----
    k_poolfinal<<<out_size / 64, 256, 0, stream>>>(out2, b2, nid, Wf, bf, outp, N);
}

// Round 6
// 183.619 us; speedup vs baseline: 4.4388x; 1.2398x over previous
//
#include <hip/hip_runtime.h>
#include <hip/hip_bf16.h>

// ---------------- helpers ----------------

__device__ __forceinline__ float lrelu02(float x) { return x > 0.f ? x : 0.2f * x; }

// round-to-nearest-even f32 -> bf16 bits
__device__ __forceinline__ unsigned short f2bf(float f) {
    unsigned b = __float_as_uint(f);
    return (unsigned short)((b + 0x7fffu + ((b >> 16) & 1u)) >> 16);
}
__device__ __forceinline__ float bf_lo(unsigned u) { return __uint_as_float(u << 16); }
__device__ __forceinline__ float bf_hi(unsigned u) { return __uint_as_float(u & 0xffff0000u); }

// ---------------- layer 1 GEMM + logits, with fused dst-histogram ----------------
__global__ __launch_bounds__(256) void k_gemm1h(
    const float* __restrict__ x, const float* __restrict__ W1,
    const float* __restrict__ a_src, const float* __restrict__ a_dst,
    unsigned short* __restrict__ H1b, float* __restrict__ asrcv, float* __restrict__ adstv, int N,
    const int* __restrict__ dst, int* __restrict__ deg, int E, int GB)
{
    if ((int)blockIdx.x >= GB) {
        const int nb = gridDim.x - GB;
        const int bi = blockIdx.x - GB;
        for (int i = bi * 256 + threadIdx.x; i < E; i += nb * 256)
            atomicAdd(&deg[dst[i]], 1);
        return;
    }

    __shared__ float sA[32][68];
    __shared__ float sB[32][128];
    const int tid = threadIdx.x;
    const int m0 = (tid >> 5) * 8;
    const int n0 = (tid & 31) * 4;
    const int rowbase = blockIdx.x * 64;

    float acc[8][4];
#pragma unroll
    for (int i = 0; i < 8; ++i)
#pragma unroll
        for (int j = 0; j < 4; ++j) acc[i][j] = 0.f;

    const int am  = tid >> 2;
    const int ak0 = (tid & 3) * 8;
    const int bk  = tid >> 3;
    const int bn0 = (tid & 7) * 16;

    for (int kt = 0; kt < 128; kt += 32) {
        int grow = rowbase + am;
        const float* xp = x + (size_t)(grow < N ? grow : N - 1) * 128 + kt + ak0;
        float4 xa = *(const float4*)(xp);
        float4 xb = *(const float4*)(xp + 4);
        sA[ak0 + 0][am] = xa.x; sA[ak0 + 1][am] = xa.y;
        sA[ak0 + 2][am] = xa.z; sA[ak0 + 3][am] = xa.w;
        sA[ak0 + 4][am] = xb.x; sA[ak0 + 5][am] = xb.y;
        sA[ak0 + 6][am] = xb.z; sA[ak0 + 7][am] = xb.w;
        const float* wp = W1 + (size_t)(kt + bk) * 128 + bn0;
#pragma unroll
        for (int q = 0; q < 4; ++q)
            *(float4*)&sB[bk][bn0 + q * 4] = *(const float4*)(wp + q * 4);
        __syncthreads();
#pragma unroll
        for (int k = 0; k < 32; ++k) {
            float4 a0 = *(const float4*)&sA[k][m0];
            float4 a1 = *(const float4*)&sA[k][m0 + 4];
            float4 b  = *(const float4*)&sB[k][n0];
            float av[8] = {a0.x, a0.y, a0.z, a0.w, a1.x, a1.y, a1.z, a1.w};
            float bv[4] = {b.x, b.y, b.z, b.w};
#pragma unroll
            for (int i = 0; i < 8; ++i)
#pragma unroll
                for (int j = 0; j < 4; ++j)
                    acc[i][j] = fmaf(av[i], bv[j], acc[i][j]);
        }
        __syncthreads();
    }

    const int h = n0 >> 5;
    const float4 asv = *(const float4*)&a_src[n0];
    const float4 adv = *(const float4*)&a_dst[n0];
#pragma unroll
    for (int i = 0; i < 8; ++i) {
        int grow = rowbase + m0 + i;
        if (grow < N) {
            uint2 p;
            p.x = (unsigned)f2bf(acc[i][0]) | ((unsigned)f2bf(acc[i][1]) << 16);
            p.y = (unsigned)f2bf(acc[i][2]) | ((unsigned)f2bf(acc[i][3]) << 16);
            *(uint2*)&H1b[(size_t)grow * 128 + n0] = p;
        }
        float vs = acc[i][0]*asv.x + acc[i][1]*asv.y + acc[i][2]*asv.z + acc[i][3]*asv.w;
        float vd = acc[i][0]*adv.x + acc[i][1]*adv.y + acc[i][2]*adv.z + acc[i][3]*adv.w;
        vs += __shfl_xor(vs, 1); vd += __shfl_xor(vd, 1);
        vs += __shfl_xor(vs, 2); vd += __shfl_xor(vd, 2);
        vs += __shfl_xor(vs, 4); vd += __shfl_xor(vd, 4);
        if ((tid & 7) == 0 && grow < N) {
            asrcv[grow * 4 + h] = vs;
            adstv[grow * 4 + h] = vd;
        }
    }
}

// ---------------- layer 2 GEMM + logits (input = relu(out1 + b1)) ----------------
__global__ __launch_bounds__(256) void k_gemm2(
    const float* __restrict__ X, const float* __restrict__ b1,
    const float* __restrict__ W2, const float* __restrict__ a_src2, const float* __restrict__ a_dst2,
    unsigned short* __restrict__ H2b, float* __restrict__ asrcv, float* __restrict__ adstv, int N)
{
    __shared__ float xs[64][132];
    __shared__ float ws[128][16];
    const int tid = threadIdx.x;
    const int rowbase = blockIdx.x * 64;
    {
        int k = tid >> 1, c0 = (tid & 1) * 8;
        *(float4*)&ws[k][c0]     = *(const float4*)&W2[k * 16 + c0];
        *(float4*)&ws[k][c0 + 4] = *(const float4*)&W2[k * 16 + c0 + 4];
    }
    {
        int r = tid >> 2, k0 = (tid & 3) * 32;
        int grow = rowbase + r;
        const float* xp = X + (size_t)(grow < N ? grow : N - 1) * 128 + k0;
#pragma unroll
        for (int q = 0; q < 8; ++q) {
            float4 v  = *(const float4*)(xp + q * 4);
            float4 bb = *(const float4*)&b1[k0 + q * 4];
            xs[r][k0 + q*4 + 0] = fmaxf(v.x + bb.x, 0.f);
            xs[r][k0 + q*4 + 1] = fmaxf(v.y + bb.y, 0.f);
            xs[r][k0 + q*4 + 2] = fmaxf(v.z + bb.z, 0.f);
            xs[r][k0 + q*4 + 3] = fmaxf(v.w + bb.w, 0.f);
        }
    }
    __syncthreads();
    const int r = tid >> 2, c0 = (tid & 3) * 4;
    float acc[4] = {0.f, 0.f, 0.f, 0.f};
#pragma unroll 16
    for (int k = 0; k < 128; ++k) {
        float xv = xs[r][k];
        float4 w = *(const float4*)&ws[k][c0];
        acc[0] = fmaf(xv, w.x, acc[0]);
        acc[1] = fmaf(xv, w.y, acc[1]);
        acc[2] = fmaf(xv, w.z, acc[2]);
        acc[3] = fmaf(xv, w.w, acc[3]);
    }
    int grow = rowbase + r;
    const float4 as4 = *(const float4*)&a_src2[c0];
    const float4 ad4 = *(const float4*)&a_dst2[c0];
    float vs = acc[0]*as4.x + acc[1]*as4.y + acc[2]*as4.z + acc[3]*as4.w;
    float vd = acc[0]*ad4.x + acc[1]*ad4.y + acc[2]*ad4.z + acc[3]*ad4.w;
    vs += __shfl_xor(vs, 1); vd += __shfl_xor(vd, 1);
    vs += __shfl_xor(vs, 2); vd += __shfl_xor(vd, 2);
    if (grow < N) {
        uint2 p;
        p.x = (unsigned)f2bf(acc[0]) | ((unsigned)f2bf(acc[1]) << 16);
        p.y = (unsigned)f2bf(acc[2]) | ((unsigned)f2bf(acc[3]) << 16);
        *(uint2*)&H2b[(size_t)grow * 16 + c0] = p;
        if ((tid & 3) == 0) { asrcv[grow] = vs; adstv[grow] = vd; }
    }
}

// ---------------- hierarchical scan (3 small kernels) ----------------
// k_s1: per-block (1024-elem tile) inclusive scan + block total
__global__ __launch_bounds__(1024) void k_s1(
    const int* __restrict__ deg, int* __restrict__ scn, int* __restrict__ bsum, int N)
{
    __shared__ int wsum[16];
    const int lane = threadIdx.x & 63, w = threadIdx.x >> 6;
    const int i = blockIdx.x * 1024 + threadIdx.x;
    int v = (i < N) ? deg[i] : 0;
    int sc = v;
#pragma unroll
    for (int s = 1; s < 64; s <<= 1) {
        int t = __shfl_up(sc, s);
        if (lane >= s) sc += t;
    }
    if (lane == 63) wsum[w] = sc;
    __syncthreads();
    if (threadIdx.x < 16) {
        int t = wsum[threadIdx.x];
#pragma unroll
        for (int s = 1; s < 16; s <<= 1) {
            int u = __shfl_up(t, s);
            if ((int)threadIdx.x >= s) t += u;
        }
        wsum[threadIdx.x] = t;
    }
    __syncthreads();
    int incl = ((w == 0) ? 0 : wsum[w - 1]) + sc;
    if (i < N) scn[i] = incl;
    if (threadIdx.x == 1023) bsum[blockIdx.x] = incl;
}

// k_s2: single-wave exclusive scan of block totals (nb <= 64)
__global__ __launch_bounds__(64) void k_s2(
    const int* __restrict__ bsum, int* __restrict__ bpre, int nb)
{
    int t = threadIdx.x;
    int v = (t < nb) ? bsum[t] : 0;
    int sc = v;
#pragma unroll
    for (int s = 1; s < 64; s <<= 1) {
        int u = __shfl_up(sc, s);
        if (t >= s) sc += u;
    }
    if (t < nb) bpre[t] = sc - v;
}

// k_s3: off[i+1] = bpre[b] + scn[i]; cur[i] = off[i+1] - deg[i]; off[0]=0
__global__ __launch_bounds__(1024) void k_s3(
    const int* __restrict__ deg, const int* __restrict__ scn, const int* __restrict__ bpre,
    int* __restrict__ off, int* __restrict__ cur, int N)
{
    const int i = blockIdx.x * 1024 + threadIdx.x;
    if (i == 0) off[0] = 0;
    if (i < N) {
        int incl = bpre[blockIdx.x] + scn[i];
        off[i + 1] = incl;
        cur[i] = incl - deg[i];
    }
}

// ---------------- XCD-partitioned scatter ----------------
__global__ __launch_bounds__(256) void k_scatterx(
    const int* __restrict__ src, const int* __restrict__ dst,
    int* __restrict__ cur, unsigned short* __restrict__ ecsr, int E, int N)
{
    const int g  = blockIdx.x & 7;
    const int lo = (int)(((long long)N * g) >> 3);
    const int hi = (int)(((long long)N * (g + 1)) >> 3);
    const int nb = gridDim.x >> 3;
    const int bi = blockIdx.x >> 3;
    for (int i = bi * 256 + threadIdx.x; i < E; i += nb * 256) {
        int d = dst[i];
        if (d >= lo && d < hi) {
            int p = atomicAdd(&cur[d], 1);
            ecsr[p] = (unsigned short)src[i];
        }
    }
}

// ---------------- fused softmax + aggregation, layer 1 ----------------
__global__ __launch_bounds__(256) void k_agg1(
    const unsigned short* __restrict__ H1b, const float* __restrict__ asrc, const float* __restrict__ adst,
    const int* __restrict__ off, const unsigned short* __restrict__ ecsr,
    float* __restrict__ out, int N)
{
    __shared__ float sEs[4][64 * 4];
    __shared__ int   sSs[4][64];
    const int w = threadIdx.x >> 6, lane = threadIdx.x & 63;
    float* sE = sEs[w];
    int*   sS = sSs[w];
    const int n = blockIdx.x * 4 + w;
    if (n >= N) return;
    const int beg = off[n], deg = off[n + 1] - beg;

    const float4 ad4 = *(const float4*)&adst[n * 4];
    const float4 as4 = *(const float4*)&asrc[n * 4];
    float es0 = __expf(lrelu02(as4.x + ad4.x));
    float es1 = __expf(lrelu02(as4.y + ad4.y));
    float es2 = __expf(lrelu02(as4.z + ad4.z));
    float es3 = __expf(lrelu02(as4.w + ad4.w));
    float ssum0 = es0, ssum1 = es1, ssum2 = es2, ssum3 = es3;
    if (lane != 0) { ssum0 = 0.f; ssum1 = 0.f; ssum2 = 0.f; ssum3 = 0.f; }

    const int g = lane >> 4, q = lane & 15;
    const int c0 = q * 8, h = q >> 2;
    float acc[8] = {0.f,0.f,0.f,0.f,0.f,0.f,0.f,0.f};

    for (int cb = 0; cb < deg; cb += 64) {
        int cnt = min(64, deg - cb);
        if (lane < cnt) {
            int s = (int)ecsr[beg + cb + lane];
            sS[lane] = s;
            const float4 a = *(const float4*)&asrc[s * 4];
            float e0 = __expf(lrelu02(a.x + ad4.x));
            float e1 = __expf(lrelu02(a.y + ad4.y));
            float e2 = __expf(lrelu02(a.z + ad4.z));
            float e3 = __expf(lrelu02(a.w + ad4.w));
            ssum0 += e0; ssum1 += e1; ssum2 += e2; ssum3 += e3;
            sE[lane * 4 + 0] = e0; sE[lane * 4 + 1] = e1;
            sE[lane * 4 + 2] = e2; sE[lane * 4 + 3] = e3;
        }
        for (int j = g; j < cnt; j += 4) {
            int s = sS[j];
            float e = sE[j * 4 + h];
            uint4 u = *(const uint4*)&H1b[(size_t)s * 128 + c0];
            acc[0] = fmaf(e, bf_lo(u.x), acc[0]);
            acc[1] = fmaf(e, bf_hi(u.x), acc[1]);
            acc[2] = fmaf(e, bf_lo(u.y), acc[2]);
            acc[3] = fmaf(e, bf_hi(u.y), acc[3]);
            acc[4] = fmaf(e, bf_lo(u.z), acc[4]);
            acc[5] = fmaf(e, bf_hi(u.z), acc[5]);
            acc[6] = fmaf(e, bf_lo(u.w), acc[6]);
            acc[7] = fmaf(e, bf_hi(u.w), acc[7]);
        }
    }

#pragma unroll
    for (int xm = 32; xm >= 1; xm >>= 1) {
        ssum0 += __shfl_xor(ssum0, xm);
        ssum1 += __shfl_xor(ssum1, xm);
        ssum2 += __shfl_xor(ssum2, xm);
        ssum3 += __shfl_xor(ssum3, xm);
    }
#pragma unroll
    for (int k = 0; k < 8; ++k) {
        acc[k] += __shfl_xor(acc[k], 16);
        acc[k] += __shfl_xor(acc[k], 32);
    }
    if (g == 0) {
        float ssv = (h == 0) ? ssum0 : (h == 1) ? ssum1 : (h == 2) ? ssum2 : ssum3;
        float esv = (h == 0) ? es0   : (h == 1) ? es1   : (h == 2) ? es2   : es3;
        float inv = 1.f / (ssv + 1e-16f);
        uint4 u = *(const uint4*)&H1b[(size_t)n * 128 + c0];
        float o[8];
        o[0] = (acc[0] + esv * bf_lo(u.x)) * inv;
        o[1] = (acc[1] + esv * bf_hi(u.x)) * inv;
        o[2] = (acc[2] + esv * bf_lo(u.y)) * inv;
        o[3] = (acc[3] + esv * bf_hi(u.y)) * inv;
        o[4] = (acc[4] + esv * bf_lo(u.z)) * inv;
        o[5] = (acc[5] + esv * bf_hi(u.z)) * inv;
        o[6] = (acc[6] + esv * bf_lo(u.w)) * inv;
        o[7] = (acc[7] + esv * bf_hi(u.w)) * inv;
        *(float4*)&out[(size_t)n * 128 + c0]     = make_float4(o[0], o[1], o[2], o[3]);
        *(float4*)&out[(size_t)n * 128 + c0 + 4] = make_float4(o[4], o[5], o[6], o[7]);
    }
}

// ---------------- fused softmax + aggregation, layer 2 ----------------
__global__ __launch_bounds__(256) void k_agg2(
    const unsigned short* __restrict__ H2b, const float* __restrict__ asrc, const float* __restrict__ adst,
    const int* __restrict__ off, const unsigned short* __restrict__ ecsr,
    float* __restrict__ out, int N)
{
    __shared__ float sEs[4][64];
    __shared__ int   sSs[4][64];
    const int w = threadIdx.x >> 6, lane = threadIdx.x & 63;
    float* sE = sEs[w];
    int*   sS = sSs[w];
    const int n = blockIdx.x * 4 + w;
    if (n >= N) return;
    const int beg = off[n], deg = off[n + 1] - beg;

    const float adv = adst[n];
    float eself = __expf(lrelu02(asrc[n] + adv));
    float ssum = (lane == 0) ? eself : 0.f;

    const int g = lane >> 3, q = lane & 7;
    const int c0 = q * 2;
    float acc0 = 0.f, acc1 = 0.f;

    for (int cb = 0; cb < deg; cb += 64) {
        int cnt = min(64, deg - cb);
        if (lane < cnt) {
            int s = (int)ecsr[beg + cb + lane];
            sS[lane] = s;
            float e = __expf(lrelu02(asrc[s] + adv));
            ssum += e;
            sE[lane] = e;
        }
        for (int j = g; j < cnt; j += 8) {
            int s = sS[j];
            float e = sE[j];
            unsigned u = *(const unsigned*)&H2b[(size_t)s * 16 + c0];
            acc0 = fmaf(e, bf_lo(u), acc0);
            acc1 = fmaf(e, bf_hi(u), acc1);
        }
    }
#pragma unroll
    for (int xm = 32; xm >= 1; xm >>= 1) ssum += __shfl_xor(ssum, xm);
    acc0 += __shfl_xor(acc0, 8);  acc1 += __shfl_xor(acc1, 8);
    acc0 += __shfl_xor(acc0, 16); acc1 += __shfl_xor(acc1, 16);
    acc0 += __shfl_xor(acc0, 32); acc1 += __shfl_xor(acc1, 32);
    if (g == 0) {
        float inv = 1.f / (ssum + 1e-16f);
        unsigned u = *(const unsigned*)&H2b[(size_t)n * 16 + c0];
        float2 o;
        o.x = (acc0 + eself * bf_lo(u)) * inv;
        o.y = (acc1 + eself * bf_hi(u)) * inv;
        *(float2*)&out[(size_t)n * 16 + c0] = o;
    }
}

// ---------------- pooling + final linear (fused) ----------------
__global__ __launch_bounds__(256) void k_poolfinal(
    const float* __restrict__ out2, const float* __restrict__ b2,
    const int* __restrict__ nodeIDs, const float* __restrict__ Wf,
    const float* __restrict__ bf, float* __restrict__ outp, int N)
{
    int g = blockIdx.x;
    int lo = 0, hi = N;
    while (lo < hi) { int mid = (lo + hi) >> 1; if (nodeIDs[mid] < g) lo = mid + 1; else hi = mid; }
    int start = lo;
    lo = 0; hi = N;
    while (lo < hi) { int mid = (lo + hi) >> 1; if (nodeIDs[mid] < g + 1) lo = mid + 1; else hi = mid; }
    int end = lo;

    int c = threadIdx.x & 15, grp = threadIdx.x >> 4;
    float bc = b2[c];
    float acc = 0.f;
    for (int n = start + grp; n < end; n += 16)
        acc += fmaxf(out2[(size_t)n * 16 + c] + bc, 0.f);

    __shared__ float sd[256];
    __shared__ float p16[16];
    sd[threadIdx.x] = acc;
    __syncthreads();
#pragma unroll
    for (int s = 8; s >= 1; s >>= 1) {
        if (grp < s) sd[threadIdx.x] += sd[(grp + s) * 16 + c];
        __syncthreads();
    }
    if (threadIdx.x < 16) {
        float cnt = (float)(end - start);
        p16[threadIdx.x] = sd[threadIdx.x] / fmaxf(cnt, 1.f);
    }
    __syncthreads();
    if (threadIdx.x < 64) {
        int o = threadIdx.x;
        float a = bf[o];
#pragma unroll
        for (int k = 0; k < 16; ++k)
            a = fmaf(p16[k], Wf[k * 64 + o], a);
        outp[(size_t)g * 64 + o] = a;
    }
}

// ---------------- launcher ----------------
extern "C" void kernel_launch(void* const* d_in, const int* in_sizes, int n_in,
                              void* d_out, int out_size, void* d_ws, size_t ws_size,
                              hipStream_t stream)
{
    const float* x   = (const float*)d_in[0];
    const int*   ei  = (const int*)  d_in[1];
    const int*   nid = (const int*)  d_in[3];
    const float* W1  = (const float*)d_in[4];
    const float* as1 = (const float*)d_in[5];
    const float* ad1 = (const float*)d_in[6];
    const float* b1  = (const float*)d_in[7];
    const float* W2  = (const float*)d_in[8];
    const float* as2 = (const float*)d_in[9];
    const float* ad2 = (const float*)d_in[10];
    const float* b2  = (const float*)d_in[11];
    const float* Wf  = (const float*)d_in[12];
    const float* bf  = (const float*)d_in[13];
    float* outp = (float*)d_out;

    const int N = in_sizes[0] / 128;
    const int E = in_sizes[1] / 2;
    const int* src = ei;
    const int* dst = ei + E;

    char* ws = (char*)d_ws;
    size_t off_b = 0;
    auto alloc = [&](size_t bytes) -> char* {
        char* p = ws + off_b;
        off_b += (bytes + 255) & ~(size_t)255;
        return p;
    };

    unsigned short* H1b  = (unsigned short*)alloc((size_t)N * 128 * 2);
    unsigned short* H2b  = (unsigned short*)alloc((size_t)N * 16 * 2);
    unsigned short* ecsr = (unsigned short*)alloc((size_t)E * 2);
    float* out1   = (float*)alloc((size_t)N * 128 * 4);
    float* asrc1  = (float*)alloc((size_t)N * 4 * 4);
    float* adst1  = (float*)alloc((size_t)N * 4 * 4);
    float* out2   = (float*)alloc((size_t)N * 16 * 4);
    float* asrc2  = (float*)alloc((size_t)N * 4);
    float* adst2  = (float*)alloc((size_t)N * 4);
    int*   deg    = (int*)  alloc((size_t)N * 4);
    int*   cur    = (int*)  alloc((size_t)N * 4);
    int*   offp   = (int*)  alloc((size_t)(N + 1) * 4);
    int*   scn    = (int*)  alloc((size_t)N * 4);
    int*   bsum   = (int*)  alloc((size_t)64 * 4);
    int*   bpre   = (int*)  alloc((size_t)64 * 4);

    auto cdiv = [](long long a, long long b) { return (int)((a + b - 1) / b); };

    const int GB = cdiv(N, 64);          // gemm1 tile blocks
    const int NB = cdiv(N, 1024);        // scan tiles (<= 64)

    // deg must start at zero (hist accumulates into it)
    hipMemsetAsync(deg, 0, (size_t)N * 4, stream);

    // ----- layer 1 GEMM + hidden histogram -----
    k_gemm1h<<<GB + 256, 256, 0, stream>>>(x, W1, as1, ad1, H1b, asrc1, adst1, N,
                                           dst, deg, E, GB);
    // ----- CSR: hierarchical scan + XCD-partitioned scatter -----
    k_s1<<<NB, 1024, 0, stream>>>(deg, scn, bsum, N);
    k_s2<<<1, 64, 0, stream>>>(bsum, bpre, NB);
    k_s3<<<NB, 1024, 0, stream>>>(deg, scn, bpre, offp, cur, N);
    k_scatterx<<<1024, 256, 0, stream>>>(src, dst, cur, ecsr, E, N);

    // ----- layer 1 aggregation -----
    k_agg1<<<cdiv(N, 4), 256, 0, stream>>>(H1b, asrc1, adst1, offp, ecsr, out1, N);

    // ----- layer 2 -----
    k_gemm2<<<cdiv(N, 64), 256, 0, stream>>>(out1, b1, W2, as2, ad2, H2b, asrc2, adst2, N);
    k_agg2<<<cdiv(N, 4), 256, 0, stream>>>(H2b, asrc2, adst2, offp, ecsr, out2, N);

    // ----- pool + final linear (fused) -----
    k_poolfinal<<<out_size / 64, 256, 0, stream>>>(out2, b2, nid, Wf, bf, outp, N);
}